// Round 1
// baseline (175.962 us; speedup 1.0000x reference)
//
#include <hip/hip_runtime.h>

typedef unsigned int u32;
typedef unsigned short u16;
typedef unsigned long long u64;
typedef __attribute__((ext_vector_type(8))) short s16x8;
typedef __attribute__((ext_vector_type(8))) __bf16 bf16x8;
typedef __attribute__((ext_vector_type(4))) float f32x4;

#define WSMB (1ull << 20)

static __device__ __forceinline__ u16 f2bf(float f) {
  u32 u = __builtin_bit_cast(u32, f);
  return (u16)((u + 0x7fffu + ((u >> 16) & 1u)) >> 16);
}

static __device__ __forceinline__ f32x4 mfma16x16(s16x8 a, s16x8 b, f32x4 c) {
  return __builtin_amdgcn_mfma_f32_16x16x32_bf16(
      __builtin_bit_cast(bf16x8, a), __builtin_bit_cast(bf16x8, b), c, 0, 0, 0);
}

#define GLOAD_LDS16(g, l)                                                      \
  __builtin_amdgcn_global_load_lds(                                            \
      (const __attribute__((address_space(1))) u32*)(const void*)(g),          \
      (__attribute__((address_space(3))) u32*)(void*)(l), 16, 0, 0)

// ---------------- fp32 -> bf16 convert ----------------
__global__ __launch_bounds__(256) void k_cvt(const float* __restrict__ s,
                                             u16* __restrict__ d, int n) {
  int i = (blockIdx.x * 256 + threadIdx.x) * 4;
  if (i >= n) return;
  float4 v = *(const float4*)(s + i);
  u64 p = (u64)f2bf(v.x) | ((u64)f2bf(v.y) << 16) | ((u64)f2bf(v.z) << 32) |
          ((u64)f2bf(v.w) << 48);
  *(u64*)(d + i) = p;
}

// ---------------- mask -> 64-bit row bitmasks ----------------
__global__ __launch_bounds__(256) void k_bits(const float* __restrict__ mask,
                                              u64* __restrict__ bits) {
  int w = threadIdx.x >> 6, l = threadIdx.x & 63;
  int r = blockIdx.x * 4 + w;  // r in [0, 4096) = b*1024+s
  float v = mask[(size_t)r * 64 + l];
  u64 bl = __ballot(v != 0.0f);
  if (l == 0) bits[r] = bl;
}

// ---------------- shared GEMM core: C128x128 += A[128xK] * Bw[128xK]^T ------
static __device__ __forceinline__ void gemm_core(const u16* __restrict__ A,
                                                 const u16* __restrict__ Bw,
                                                 f32x4 (&acc)[4][4]) {
  __shared__ __attribute__((aligned(16))) u16 As[4096];
  __shared__ __attribute__((aligned(16))) u16 Bs[4096];
  const int t = threadIdx.x;
  const int l = t & 63, w = t >> 6, lr = l & 15, lk = l >> 4;
  const int amr = (w & 1) * 64, bnr = (w >> 1) * 64;
  const int c0 = t, c1 = t + 256;
  const u16* Ag0 = A + (size_t)(c0 >> 2) * 1024 + (c0 & 3) * 8;
  const u16* Ag1 = A + (size_t)(c1 >> 2) * 1024 + (c1 & 3) * 8;
  const u16* Bg0 = Bw + (size_t)(c0 >> 2) * 1024 + (c0 & 3) * 8;
  const u16* Bg1 = Bw + (size_t)(c1 >> 2) * 1024 + (c1 & 3) * 8;
  for (int kt = 0; kt < 1024; kt += 32) {
    GLOAD_LDS16(Ag0 + kt, As + c0 * 8);
    GLOAD_LDS16(Ag1 + kt, As + c1 * 8);
    GLOAD_LDS16(Bg0 + kt, Bs + c0 * 8);
    GLOAD_LDS16(Bg1 + kt, Bs + c1 * 8);
    __syncthreads();
    s16x8 af[4], bf[4];
#pragma unroll
    for (int i = 0; i < 4; i++)
      af[i] = *(const s16x8*)(As + (amr + i * 16 + lr) * 32 + lk * 8);
#pragma unroll
    for (int j = 0; j < 4; j++)
      bf[j] = *(const s16x8*)(Bs + (bnr + j * 16 + lr) * 32 + lk * 8);
#pragma unroll
    for (int i = 0; i < 4; i++)
#pragma unroll
      for (int j = 0; j < 4; j++)
        acc[i][j] = mfma16x16(af[i], bf[j], acc[i][j]);
    __syncthreads();
  }
}

// ---------------- fused QKV projection ----------------
// grid 768: proj = bid/256 (0=q,1=k,2=v); rem: mb = rem/8, nb = rem%8
__global__ __launch_bounds__(256) void k_qkv(
    const u16* __restrict__ Xq, const u16* __restrict__ Xk,
    const u16* __restrict__ Xv, const u16* __restrict__ Wqb,
    const u16* __restrict__ Wkb, const u16* __restrict__ Wvb,
    const float* __restrict__ bq, const float* __restrict__ bk,
    const float* __restrict__ bv, u16* __restrict__ Qo, u16* __restrict__ Ko,
    u16* __restrict__ Vto) {
  const int bid = blockIdx.x;
  const int proj = bid >> 8;
  const int rem = bid & 255;
  const int mb = rem >> 3, nb = rem & 7;
  const u16* A = proj == 0 ? Xq : (proj == 1 ? Xk : Xv);
  const u16* Bw = proj == 0 ? Wqb : (proj == 1 ? Wkb : Wvb);
  const float* bias = proj == 0 ? bq : (proj == 1 ? bk : bv);
  f32x4 acc[4][4] = {};
  gemm_core(A + (size_t)mb * 128 * 1024, Bw + (size_t)nb * 128 * 1024, acc);
  const int t = threadIdx.x;
  const int l = t & 63, w = t >> 6, lr = l & 15, lk = l >> 4;
  const int amr = (w & 1) * 64, bnr = (w >> 1) * 64;
#pragma unroll
  for (int i = 0; i < 4; i++) {
    const int m0 = mb * 128 + amr + i * 16 + lk * 4;
#pragma unroll
    for (int j = 0; j < 4; j++) {
      const int n = nb * 128 + bnr + j * 16 + lr;
      const float bv_ = bias[n];
      const int h = n >> 6, dd = n & 63;
#pragma unroll
      for (int r = 0; r < 4; r++) {
        const int m = m0 + r;
        const int b_ = m >> 10, s = m & 1023;
        const float v = acc[i][j][r] + bv_;
        if (proj < 2) {
          u16* O = proj ? Ko : Qo;
          O[((size_t)((b_ * 16 + h) * 1024 + s)) * 64 + dd] = f2bf(v);
        } else {
          Vto[((size_t)((b_ * 16 + h) * 64 + dd)) * 1024 + s] = f2bf(v);
        }
      }
    }
  }
}

// ---------------- output projection: d_out = xbuf @ Wo^T (fp32 out) --------
__global__ __launch_bounds__(256) void k_oproj(const u16* __restrict__ Xb,
                                               const u16* __restrict__ Wob,
                                               float* __restrict__ Out) {
  const int mb = blockIdx.x >> 3, nb = blockIdx.x & 7;
  f32x4 acc[4][4] = {};
  gemm_core(Xb + (size_t)mb * 128 * 1024, Wob + (size_t)nb * 128 * 1024, acc);
  const int t = threadIdx.x;
  const int l = t & 63, w = t >> 6, lr = l & 15, lk = l >> 4;
  const int amr = (w & 1) * 64, bnr = (w >> 1) * 64;
#pragma unroll
  for (int i = 0; i < 4; i++)
#pragma unroll
    for (int j = 0; j < 4; j++)
#pragma unroll
      for (int r = 0; r < 4; r++) {
        const int m = mb * 128 + amr + i * 16 + lk * 4 + r;
        const int n = nb * 128 + bnr + j * 16 + lr;
        Out[(size_t)m * 1024 + n] = acc[i][j][r];
      }
}

// ---------------- flash attention ----------------
// grid 1024: hb = bid>>4 (h = hb>>2, b = hb&3), qt = bid&15
__global__ __launch_bounds__(256) void k_attn(const u16* __restrict__ Qb,
                                              const u16* __restrict__ Kb,
                                              const u16* __restrict__ Vt,
                                              const u64* __restrict__ bits,
                                              u16* __restrict__ xbuf) {
  __shared__ __attribute__((aligned(16))) u16 Ks[4096];
  __shared__ __attribute__((aligned(16))) u16 Vs[4096];
  __shared__ __attribute__((aligned(16))) u16 Ps[4096];
  const int t = threadIdx.x, l = t & 63, w = t >> 6, lr = l & 15, lk = l >> 4;
  const int qt = blockIdx.x & 15, hb = blockIdx.x >> 4;
  const int h = hb >> 2, b = hb & 3;
  const int s0 = qt * 64;
  const u16* Qhb = Qb + (size_t)(b * 16 + h) * 65536;
  const u16* Khb = Kb + (size_t)(b * 16 + h) * 65536;
  const u16* Vhb = Vt + (size_t)(b * 16 + h) * 65536;
  const u64* bitsb = bits + b * 1024;

  const int qrow = s0 + w * 16 + lr;
  s16x8 qf0 = *(const s16x8*)(Qhb + (size_t)qrow * 64 + lk * 8);
  s16x8 qf1 = *(const s16x8*)(Qhb + (size_t)qrow * 64 + 32 + lk * 8);
  u64 bq[4];
#pragma unroll
  for (int r = 0; r < 4; r++) bq[r] = bitsb[s0 + w * 16 + lk * 4 + r];

  f32x4 xa[4] = {};
  float m_[4], ls[4];
#pragma unroll
  for (int r = 0; r < 4; r++) {
    m_[r] = -__builtin_inff();
    ls[r] = 0.f;
  }

  // staging geometry (pre-swizzled global source, linear LDS dest)
  const int ca = t, cb_ = t + 256;
  const int rA = ca >> 3, colA = (ca & 7) * 16;
  const int rB = cb_ >> 3, colB = (cb_ & 7) * 16;
  const int sA = colA ^ ((rA & 7) << 4);
  const int sB = colB ^ ((rB & 7) << 4);

  for (int kt = 0; kt < 16; kt++) {
    const int kb = kt * 64;
    GLOAD_LDS16(Khb + (size_t)(kb + rA) * 64 + (sA >> 1), Ks + ca * 8);
    GLOAD_LDS16(Khb + (size_t)(kb + rB) * 64 + (sB >> 1), Ks + cb_ * 8);
    GLOAD_LDS16(Vhb + (size_t)rA * 1024 + kb + (sA >> 1), Vs + ca * 8);
    GLOAD_LDS16(Vhb + (size_t)rB * 1024 + kb + (sB >> 1), Vs + cb_ * 8);
    __syncthreads();

    // QK^T for 64 keys (4 col-blocks of 16)
    float p[4][4];
#pragma unroll
    for (int nb = 0; nb < 4; nb++) {
      const int krow = nb * 16 + lr;
      const int sw = (krow & 7) << 4;
      s16x8 k0 = *(const s16x8*)((const char*)Ks + krow * 128 + ((lk * 16) ^ sw));
      s16x8 k1 =
          *(const s16x8*)((const char*)Ks + krow * 128 + ((64 + lk * 16) ^ sw));
      f32x4 z = {};
      z = mfma16x16(qf0, k0, z);
      z = mfma16x16(qf1, k1, z);
      const u64 bkv = bitsb[kb + nb * 16 + lr];
#pragma unroll
      for (int r = 0; r < 4; r++)
        p[nb][r] = (bq[r] & bkv) ? z[r] * 0.125f : -1e9f;
    }

    // wave-parallel online softmax (16-lane groups hold a full row)
    float tm[4], ts[4];
#pragma unroll
    for (int r = 0; r < 4; r++)
      tm[r] = fmaxf(fmaxf(p[0][r], p[1][r]), fmaxf(p[2][r], p[3][r]));
#pragma unroll
    for (int o = 1; o < 16; o <<= 1)
#pragma unroll
      for (int r = 0; r < 4; r++) tm[r] = fmaxf(tm[r], __shfl_xor(tm[r], o));
#pragma unroll
    for (int r = 0; r < 4; r++) {
      const float mn = fmaxf(m_[r], tm[r]);
      const float scl = __expf(m_[r] - mn);
      m_[r] = mn;
      float s_ = 0.f;
#pragma unroll
      for (int nb = 0; nb < 4; nb++) {
        p[nb][r] = __expf(p[nb][r] - mn);
        s_ += p[nb][r];
      }
      ts[r] = s_;
      ls[r] *= scl;
#pragma unroll
      for (int nd = 0; nd < 4; nd++) xa[nd][r] *= scl;
    }
#pragma unroll
    for (int o = 1; o < 16; o <<= 1)
#pragma unroll
      for (int r = 0; r < 4; r++) ts[r] += __shfl_xor(ts[r], o);
#pragma unroll
    for (int r = 0; r < 4; r++) ls[r] += ts[r];

    // P -> per-wave swizzled LDS (transpose for PV A-operand)
    u16* Pw = Ps + w * 1024;
#pragma unroll
    for (int nb = 0; nb < 4; nb++)
#pragma unroll
      for (int r = 0; r < 4; r++) {
        const int prow = lk * 4 + r;
        const int cbyte = (nb * 32 + 2 * lr) ^ ((prow & 7) << 4);
        *(u16*)((char*)Pw + prow * 128 + cbyte) = f2bf(p[nb][r]);
      }
    const int asw = (lr & 7) << 4;
    s16x8 pa0 = *(const s16x8*)((const char*)Pw + lr * 128 + ((lk * 16) ^ asw));
    s16x8 pa1 =
        *(const s16x8*)((const char*)Pw + lr * 128 + ((64 + lk * 16) ^ asw));

    // PV accumulate
#pragma unroll
    for (int nd = 0; nd < 4; nd++) {
      const int vrow = nd * 16 + lr;
      const int vsw = (vrow & 7) << 4;
      s16x8 v0 = *(const s16x8*)((const char*)Vs + vrow * 128 + ((lk * 16) ^ vsw));
      s16x8 v1 =
          *(const s16x8*)((const char*)Vs + vrow * 128 + ((64 + lk * 16) ^ vsw));
      xa[nd] = mfma16x16(pa0, v0, xa[nd]);
      xa[nd] = mfma16x16(pa1, v1, xa[nd]);
    }
    __syncthreads();
  }

  // epilogue: normalize + write in the reference's mixed reshape layout
#pragma unroll
  for (int r = 0; r < 4; r++) {
    const int s = s0 + w * 16 + lk * 4 + r;
    const float inv = 1.0f / ls[r];
    const size_t rowb = (size_t)b * 1048576 +
                        (size_t)(h * 64 + (s >> 4)) * 1024 + (s & 15) * 64;
#pragma unroll
    for (int nd = 0; nd < 4; nd++)
      xbuf[rowb + nd * 16 + lr] = f2bf(xa[nd][r] * inv);
  }
}

extern "C" void kernel_launch(void* const* d_in, const int* in_sizes, int n_in,
                              void* d_out, int out_size, void* d_ws,
                              size_t ws_size, hipStream_t stream) {
  const float* query = (const float*)d_in[0];
  const float* key_ = (const float*)d_in[1];
  const float* value = (const float*)d_in[2];
  const float* mask = (const float*)d_in[3];
  const float* bq = (const float*)d_in[5];
  const float* bk = (const float*)d_in[7];
  const float* bv = (const float*)d_in[9];
  const float* Wq = (const float*)d_in[4];
  const float* Wk = (const float*)d_in[6];
  const float* Wv = (const float*)d_in[8];
  const float* Wo = (const float*)d_in[10];

  char* ws = (char*)d_ws;
  u16* Xq = (u16*)(ws + 0 * WSMB);  // reused as xbuf after QKV GEMM
  u16* Xk = (u16*)(ws + 8 * WSMB);
  u16* Xv = (u16*)(ws + 16 * WSMB);
  u16* Wqb = (u16*)(ws + 24 * WSMB);
  u16* Wkb = (u16*)(ws + 26 * WSMB);
  u16* Wvb = (u16*)(ws + 28 * WSMB);
  u16* Wob = (u16*)(ws + 30 * WSMB);
  u16* Qb = (u16*)(ws + 32 * WSMB);
  u16* Kb = (u16*)(ws + 40 * WSMB);
  u16* Vt = (u16*)(ws + 48 * WSMB);
  u64* bits = (u64*)(ws + 56 * WSMB);
  u16* xbuf = Xq;

  k_cvt<<<4096, 256, 0, stream>>>(query, Xq, 4194304);
  k_cvt<<<4096, 256, 0, stream>>>(key_, Xk, 4194304);
  k_cvt<<<4096, 256, 0, stream>>>(value, Xv, 4194304);
  k_cvt<<<1024, 256, 0, stream>>>(Wq, Wqb, 1048576);
  k_cvt<<<1024, 256, 0, stream>>>(Wk, Wkb, 1048576);
  k_cvt<<<1024, 256, 0, stream>>>(Wv, Wvb, 1048576);
  k_cvt<<<1024, 256, 0, stream>>>(Wo, Wob, 1048576);
  k_bits<<<1024, 256, 0, stream>>>(mask, bits);
  k_qkv<<<768, 256, 0, stream>>>(Xq, Xk, Xv, Wqb, Wkb, Wvb, bq, bk, bv, Qb, Kb,
                                 Vt);
  k_attn<<<1024, 256, 0, stream>>>(Qb, Kb, Vt, bits, xbuf);
  k_oproj<<<256, 256, 0, stream>>>(xbuf, Wob, (float*)d_out);
}

// Round 2
// 147.253 us; speedup vs baseline: 1.1950x; 1.1950x over previous
//
#include <hip/hip_runtime.h>

typedef unsigned int u32;
typedef unsigned short u16;
typedef unsigned long long u64;
typedef __attribute__((ext_vector_type(8))) short s16x8;
typedef __attribute__((ext_vector_type(8))) __bf16 bf16x8;
typedef __attribute__((ext_vector_type(4))) float f32x4;

#define WSMB (1ull << 20)

static __device__ __forceinline__ u16 f2bf(float f) {
  u32 u = __builtin_bit_cast(u32, f);
  return (u16)((u + 0x7fffu + ((u >> 16) & 1u)) >> 16);
}

// v_cvt_pk_bf16_f32: low16 = bf16(lo), high16 = bf16(hi)  (RNE)
static __device__ __forceinline__ u32 pkbf(float lo, float hi) {
  u32 r;
  asm("v_cvt_pk_bf16_f32 %0, %1, %2" : "=v"(r) : "v"(lo), "v"(hi));
  return r;
}

static __device__ __forceinline__ f32x4 mfma16x16(s16x8 a, s16x8 b, f32x4 c) {
  return __builtin_amdgcn_mfma_f32_16x16x32_bf16(
      __builtin_bit_cast(bf16x8, a), __builtin_bit_cast(bf16x8, b), c, 0, 0, 0);
}

#define GLOAD_LDS16(g, l)                                                      \
  __builtin_amdgcn_global_load_lds(                                            \
      (const __attribute__((address_space(1))) u32*)(const void*)(g),          \
      (__attribute__((address_space(3))) u32*)(void*)(l), 16, 0, 0)

// ---------------- fp32 -> bf16 converts (merged launches) ----------------
__global__ __launch_bounds__(256) void k_cvt3(const float* __restrict__ a,
                                              const float* __restrict__ b,
                                              const float* __restrict__ c,
                                              u16* __restrict__ oa,
                                              u16* __restrict__ ob,
                                              u16* __restrict__ oc) {
  const float* s;
  u16* d;
  if (blockIdx.y == 0) { s = a; d = oa; }
  else if (blockIdx.y == 1) { s = b; d = ob; }
  else { s = c; d = oc; }
  int i = (blockIdx.x * 256 + threadIdx.x) * 4;
  float4 v = *(const float4*)(s + i);
  u64 p = (u64)f2bf(v.x) | ((u64)f2bf(v.y) << 16) | ((u64)f2bf(v.z) << 32) |
          ((u64)f2bf(v.w) << 48);
  *(u64*)(d + i) = p;
}

__global__ __launch_bounds__(256) void k_cvt4(const float* __restrict__ a,
                                              const float* __restrict__ b,
                                              const float* __restrict__ c,
                                              const float* __restrict__ e,
                                              u16* __restrict__ oa,
                                              u16* __restrict__ ob,
                                              u16* __restrict__ oc,
                                              u16* __restrict__ oe) {
  const float* s;
  u16* d;
  if (blockIdx.y == 0) { s = a; d = oa; }
  else if (blockIdx.y == 1) { s = b; d = ob; }
  else if (blockIdx.y == 2) { s = c; d = oc; }
  else { s = e; d = oe; }
  int i = (blockIdx.x * 256 + threadIdx.x) * 4;
  float4 v = *(const float4*)(s + i);
  u64 p = (u64)f2bf(v.x) | ((u64)f2bf(v.y) << 16) | ((u64)f2bf(v.z) << 32) |
          ((u64)f2bf(v.w) << 48);
  *(u64*)(d + i) = p;
}

// ---------------- mask -> 64-bit row bitmasks ----------------
__global__ __launch_bounds__(256) void k_bits(const float* __restrict__ mask,
                                              u64* __restrict__ bits) {
  int w = threadIdx.x >> 6, l = threadIdx.x & 63;
  int r = blockIdx.x * 4 + w;  // r in [0, 4096) = b*1024+s
  float v = mask[(size_t)r * 64 + l];
  u64 bl = __ballot(v != 0.0f);
  if (l == 0) bits[r] = bl;
}

// ---------------- mask bit-matrix: MB[qg][kt] bit j = row qg visible key kt*64+j
__global__ __launch_bounds__(256) void k_mm(const u64* __restrict__ bits,
                                            u64* __restrict__ MB) {
  int wv = threadIdx.x >> 6, l = threadIdx.x & 63;
  int qg = blockIdx.x * 4 + wv;  // 0..4095
  u64 bq = bits[qg];
  const u64* bb = bits + (qg & ~1023);
  u64* out = MB + (size_t)qg * 16;
  for (int kt = 0; kt < 16; kt++) {
    u64 bk = bb[kt * 64 + l];
    u64 m = __ballot((bq & bk) != 0ull);
    if (l == 0) out[kt] = m;
  }
}

// ---------------- shared GEMM core: C128x128 += A[128xK] * Bw[128xK]^T ------
static __device__ __forceinline__ void gemm_core(const u16* __restrict__ A,
                                                 const u16* __restrict__ Bw,
                                                 f32x4 (&acc)[4][4]) {
  __shared__ __attribute__((aligned(16))) u16 As[4096];
  __shared__ __attribute__((aligned(16))) u16 Bs[4096];
  const int t = threadIdx.x;
  const int l = t & 63, w = t >> 6, lr = l & 15, lk = l >> 4;
  const int amr = (w & 1) * 64, bnr = (w >> 1) * 64;
  const int c0 = t, c1 = t + 256;
  const u16* Ag0 = A + (size_t)(c0 >> 2) * 1024 + (c0 & 3) * 8;
  const u16* Ag1 = A + (size_t)(c1 >> 2) * 1024 + (c1 & 3) * 8;
  const u16* Bg0 = Bw + (size_t)(c0 >> 2) * 1024 + (c0 & 3) * 8;
  const u16* Bg1 = Bw + (size_t)(c1 >> 2) * 1024 + (c1 & 3) * 8;
  for (int kt = 0; kt < 1024; kt += 32) {
    GLOAD_LDS16(Ag0 + kt, As + c0 * 8);
    GLOAD_LDS16(Ag1 + kt, As + c1 * 8);
    GLOAD_LDS16(Bg0 + kt, Bs + c0 * 8);
    GLOAD_LDS16(Bg1 + kt, Bs + c1 * 8);
    __syncthreads();
    s16x8 af[4], bf[4];
#pragma unroll
    for (int i = 0; i < 4; i++)
      af[i] = *(const s16x8*)(As + (amr + i * 16 + lr) * 32 + lk * 8);
#pragma unroll
    for (int j = 0; j < 4; j++)
      bf[j] = *(const s16x8*)(Bs + (bnr + j * 16 + lr) * 32 + lk * 8);
    __builtin_amdgcn_s_setprio(1);
#pragma unroll
    for (int i = 0; i < 4; i++)
#pragma unroll
      for (int j = 0; j < 4; j++)
        acc[i][j] = mfma16x16(af[i], bf[j], acc[i][j]);
    __builtin_amdgcn_s_setprio(0);
    __syncthreads();
  }
}

// ---------------- fused QKV projection ----------------
__global__ __launch_bounds__(256) void k_qkv(
    const u16* __restrict__ Xq, const u16* __restrict__ Xk,
    const u16* __restrict__ Xv, const u16* __restrict__ Wqb,
    const u16* __restrict__ Wkb, const u16* __restrict__ Wvb,
    const float* __restrict__ bq, const float* __restrict__ bk,
    const float* __restrict__ bv, u16* __restrict__ Qo, u16* __restrict__ Ko,
    u16* __restrict__ Vto) {
  const int bid0 = blockIdx.x;
  const int bid = (bid0 & 7) * 96 + (bid0 >> 3);  // XCD swizzle (768%8==0)
  const int proj = bid >> 8;
  const int rem = bid & 255;
  const int mb = rem >> 3, nb = rem & 7;
  const u16* A = proj == 0 ? Xq : (proj == 1 ? Xk : Xv);
  const u16* Bw = proj == 0 ? Wqb : (proj == 1 ? Wkb : Wvb);
  const float* bias = proj == 0 ? bq : (proj == 1 ? bk : bv);
  f32x4 acc[4][4] = {};
  gemm_core(A + (size_t)mb * 128 * 1024, Bw + (size_t)nb * 128 * 1024, acc);
  const int t = threadIdx.x;
  const int l = t & 63, w = t >> 6, lr = l & 15, lk = l >> 4;
  const int amr = (w & 1) * 64, bnr = (w >> 1) * 64;
#pragma unroll
  for (int i = 0; i < 4; i++) {
    const int m0 = mb * 128 + amr + i * 16 + lk * 4;
#pragma unroll
    for (int j = 0; j < 4; j++) {
      const int n = nb * 128 + bnr + j * 16 + lr;
      const float bv_ = bias[n];
      const int h = n >> 6, dd = n & 63;
#pragma unroll
      for (int r = 0; r < 4; r++) {
        const int m = m0 + r;
        const int b_ = m >> 10, s = m & 1023;
        const float v = acc[i][j][r] + bv_;
        if (proj < 2) {
          u16* O = proj ? Ko : Qo;
          O[((size_t)((b_ * 16 + h) * 1024 + s)) * 64 + dd] = f2bf(v);
        } else {
          Vto[((size_t)((b_ * 16 + h) * 64 + dd)) * 1024 + s] = f2bf(v);
        }
      }
    }
  }
}

// ---------------- output projection ----------------
__global__ __launch_bounds__(256) void k_oproj(const u16* __restrict__ Xb,
                                               const u16* __restrict__ Wob,
                                               float* __restrict__ Out) {
  const int bid0 = blockIdx.x;
  const int bid = (bid0 & 7) * 32 + (bid0 >> 3);  // XCD swizzle (256%8==0)
  const int mb = bid >> 3, nb = bid & 7;
  f32x4 acc[4][4] = {};
  gemm_core(Xb + (size_t)mb * 128 * 1024, Wob + (size_t)nb * 128 * 1024, acc);
  const int t = threadIdx.x;
  const int l = t & 63, w = t >> 6, lr = l & 15, lk = l >> 4;
  const int amr = (w & 1) * 64, bnr = (w >> 1) * 64;
#pragma unroll
  for (int i = 0; i < 4; i++)
#pragma unroll
    for (int j = 0; j < 4; j++)
#pragma unroll
      for (int r = 0; r < 4; r++) {
        const int m = mb * 128 + amr + i * 16 + lk * 4 + r;
        const int n = nb * 128 + bnr + j * 16 + lr;
        Out[(size_t)m * 1024 + n] = acc[i][j][r];
      }
}

// ---------------- flash attention (swapped QK^T, per-lane softmax) ---------
__global__ __launch_bounds__(256, 4) void k_attn(const u16* __restrict__ Qb,
                                                 const u16* __restrict__ Kb,
                                                 const u16* __restrict__ Vt,
                                                 const u64* __restrict__ MB,
                                                 u16* __restrict__ xbuf) {
  __shared__ __attribute__((aligned(16))) u16 Ks[2][4096];
  __shared__ __attribute__((aligned(16))) u16 Vs[2][4096];
  __shared__ __attribute__((aligned(16))) u16 Ps[4][1024];
  const int t = threadIdx.x, l = t & 63, w = t >> 6, lr = l & 15, lk = l >> 4;
  const int bid = (blockIdx.x & 7) * 128 + (blockIdx.x >> 3);  // XCD swizzle
  const int qt = bid & 15, hb = bid >> 4;
  const int h = hb >> 2, b = hb & 3;
  const int s0 = qt * 64;
  const u16* Qhb = Qb + (size_t)(b * 16 + h) * 65536;
  const u16* Khb = Kb + (size_t)(b * 16 + h) * 65536;
  const u16* Vhb = Vt + (size_t)(b * 16 + h) * 65536;
  const int q = s0 + w * 16 + lr;  // this lane's q (output column)
  const u64* MBq = MB + ((size_t)b * 1024 + q) * 16;

  // Q fragments (B-operand): lane holds Q[q][d-slice lk*8..]
  s16x8 qf0 = *(const s16x8*)(Qhb + (size_t)q * 64 + lk * 8);
  s16x8 qf1 = *(const s16x8*)(Qhb + (size_t)q * 64 + 32 + lk * 8);

  f32x4 xa[4] = {};  // out^T: xa[nd][r] = O[d = nd*16+lk*4+r][q]
  float m_ = -__builtin_inff(), ls = 0.f;

  // staging geometry (pre-swizzled global source, linear LDS dest)
  const int ca = t, cb_ = t + 256;
  const int rA = ca >> 3, colA = (ca & 7) * 16;
  const int rB = cb_ >> 3, colB = (cb_ & 7) * 16;
  const int sA = colA ^ ((rA & 7) << 4);
  const int sB = colB ^ ((rB & 7) << 4);
  const u16* KgA = Khb + (size_t)rA * 64 + (sA >> 1);
  const u16* KgB = Khb + (size_t)rB * 64 + (sB >> 1);
  const u16* VgA = Vhb + (size_t)rA * 1024 + (sA >> 1);
  const u16* VgB = Vhb + (size_t)rB * 1024 + (sB >> 1);

  // prologue: stage tile 0 into buffer 0
  GLOAD_LDS16(KgA, &Ks[0][ca * 8]);
  GLOAD_LDS16(KgB, &Ks[0][cb_ * 8]);
  GLOAD_LDS16(VgA, &Vs[0][ca * 8]);
  GLOAD_LDS16(VgB, &Vs[0][cb_ * 8]);

  int cur = 0;
  for (int kt = 0; kt < 16; kt++) {
    __syncthreads();  // drains cur-tile loads (vmcnt0) + prior compute
    if (kt < 15) {    // prefetch next tile into the other buffer
      const int nxt = cur ^ 1;
      GLOAD_LDS16(KgA + (kt + 1) * 4096, &Ks[nxt][ca * 8]);
      GLOAD_LDS16(KgB + (kt + 1) * 4096, &Ks[nxt][cb_ * 8]);
      GLOAD_LDS16(VgA + (kt + 1) * 64, &Vs[nxt][ca * 8]);
      GLOAD_LDS16(VgB + (kt + 1) * 64, &Vs[nxt][cb_ * 8]);
    }
    const u16* Kc = Ks[cur];
    const u16* Vc = Vs[cur];

    // swapped QK^T: z[nb] rows = keys, cols = q
    u64 mw = MBq[kt];
    u32 mlo = (u32)(mw >> (lk * 4));
    u32 mhi = (u32)(mw >> (lk * 4 + 32));
    float p[4][4];
#pragma unroll
    for (int nb = 0; nb < 4; nb++) {
      const int krow = nb * 16 + lr;
      const int sw = (krow & 7) << 4;
      s16x8 k0 = *(const s16x8*)((const char*)Kc + krow * 128 + ((lk * 16) ^ sw));
      s16x8 k1 =
          *(const s16x8*)((const char*)Kc + krow * 128 + ((64 + lk * 16) ^ sw));
      f32x4 z = {};
      __builtin_amdgcn_s_setprio(1);
      z = mfma16x16(k0, qf0, z);
      z = mfma16x16(k1, qf1, z);
      __builtin_amdgcn_s_setprio(0);
#pragma unroll
      for (int r = 0; r < 4; r++) p[nb][r] = z[r] * 0.125f;
    }

    // per-lane online softmax (lane owns q; 16 keys in-register, 4 lk groups)
    float tm = fmaxf(fmaxf(p[0][0], p[0][1]), fmaxf(p[0][2], p[0][3]));
#pragma unroll
    for (int nb = 1; nb < 4; nb++)
      tm = fmaxf(tm,
                 fmaxf(fmaxf(p[nb][0], p[nb][1]), fmaxf(p[nb][2], p[nb][3])));
    tm = fmaxf(tm, __shfl_xor(tm, 16));
    tm = fmaxf(tm, __shfl_xor(tm, 32));
    const float mn = fmaxf(m_, tm);
    const float scl = __expf(m_ - mn);
    m_ = mn;
    float ts = 0.f;
#pragma unroll
    for (int nb = 0; nb < 4; nb++) {
      const u32 mword = (nb & 2) ? mhi : mlo;
#pragma unroll
      for (int r = 0; r < 4; r++) {
        float e = __expf(p[nb][r] - mn);
        e = ((mword >> ((nb & 1) * 16 + r)) & 1u) ? e : 0.f;
        p[nb][r] = e;
        ts += e;
      }
    }
    ts += __shfl_xor(ts, 16);
    ts += __shfl_xor(ts, 32);
    ls = ls * scl + ts;
#pragma unroll
    for (int nd = 0; nd < 4; nd++) xa[nd] *= scl;

    // P -> LDS (row = q, 64 keys), swizzled; hw cvt_pk packs pairs
    char* Pw = (char*)&Ps[w][0];
#pragma unroll
    for (int nb = 0; nb < 4; nb++) {
      u32 w0 = pkbf(p[nb][0], p[nb][1]);
      u32 w1 = pkbf(p[nb][2], p[nb][3]);
      *(u64*)(Pw + lr * 128 + ((nb * 32 + lk * 8) ^ ((lr & 7) << 4))) =
          (u64)w0 | ((u64)w1 << 32);
    }
    const int sw2 = (lr & 7) << 4;
    s16x8 pb0 = *(const s16x8*)(Pw + lr * 128 + ((lk * 16) ^ sw2));
    s16x8 pb1 = *(const s16x8*)(Pw + lr * 128 + ((64 + lk * 16) ^ sw2));

    // PV: out^T = V^T * P  (A = V^T rows d, B = P cols q)
    __builtin_amdgcn_s_setprio(1);
#pragma unroll
    for (int nd = 0; nd < 4; nd++) {
      const int vrow = nd * 16 + lr;
      const int vsw = (vrow & 7) << 4;
      s16x8 v0 = *(const s16x8*)((const char*)Vc + vrow * 128 + ((lk * 16) ^ vsw));
      s16x8 v1 =
          *(const s16x8*)((const char*)Vc + vrow * 128 + ((64 + lk * 16) ^ vsw));
      xa[nd] = mfma16x16(v0, pb0, xa[nd]);
      xa[nd] = mfma16x16(v1, pb1, xa[nd]);
    }
    __builtin_amdgcn_s_setprio(0);
    cur ^= 1;
  }

  // epilogue: normalize + write in the reference's mixed reshape layout
  const float inv = 1.0f / ls;
  const size_t rowb = (size_t)b * 1048576 + (size_t)(h * 64 + (q >> 4)) * 1024 +
                      (size_t)(q & 15) * 64;
#pragma unroll
  for (int nd = 0; nd < 4; nd++) {
    u32 e0 = pkbf(xa[nd][0] * inv, xa[nd][1] * inv);
    u32 e1 = pkbf(xa[nd][2] * inv, xa[nd][3] * inv);
    *(u64*)(xbuf + rowb + nd * 16 + lk * 4) = (u64)e0 | ((u64)e1 << 32);
  }
}

extern "C" void kernel_launch(void* const* d_in, const int* in_sizes, int n_in,
                              void* d_out, int out_size, void* d_ws,
                              size_t ws_size, hipStream_t stream) {
  const float* query = (const float*)d_in[0];
  const float* key_ = (const float*)d_in[1];
  const float* value = (const float*)d_in[2];
  const float* mask = (const float*)d_in[3];
  const float* bq = (const float*)d_in[5];
  const float* bk = (const float*)d_in[7];
  const float* bv = (const float*)d_in[9];
  const float* Wq = (const float*)d_in[4];
  const float* Wk = (const float*)d_in[6];
  const float* Wv = (const float*)d_in[8];
  const float* Wo = (const float*)d_in[10];

  char* ws = (char*)d_ws;
  u16* Xq = (u16*)(ws + 0 * WSMB);   // reused as xbuf after QKV GEMM
  u16* Xk = (u16*)(ws + 8 * WSMB);   // reused as MB after QKV GEMM
  u16* Xv = (u16*)(ws + 16 * WSMB);
  u16* Wqb = (u16*)(ws + 24 * WSMB);
  u16* Wkb = (u16*)(ws + 26 * WSMB);
  u16* Wvb = (u16*)(ws + 28 * WSMB);
  u16* Wob = (u16*)(ws + 30 * WSMB);
  u16* Qb = (u16*)(ws + 32 * WSMB);
  u16* Kb = (u16*)(ws + 40 * WSMB);
  u16* Vt = (u16*)(ws + 48 * WSMB);
  u64* bits = (u64*)(ws + 56 * WSMB);
  u64* MBm = (u64*)(ws + 8 * WSMB);  // 512 KB, overlaps dead Xk
  u16* xbuf = Xq;

  k_cvt3<<<dim3(4096, 3), 256, 0, stream>>>(query, key_, value, Xq, Xk, Xv);
  k_cvt4<<<dim3(1024, 4), 256, 0, stream>>>(Wq, Wk, Wv, Wo, Wqb, Wkb, Wvb, Wob);
  k_bits<<<1024, 256, 0, stream>>>(mask, bits);
  k_qkv<<<768, 256, 0, stream>>>(Xq, Xk, Xv, Wqb, Wkb, Wvb, bq, bk, bv, Qb, Kb,
                                 Vt);
  k_mm<<<1024, 256, 0, stream>>>(bits, MBm);
  k_attn<<<1024, 256, 0, stream>>>(Qb, Kb, Vt, MBm, xbuf);
  k_oproj<<<256, 256, 0, stream>>>(xbuf, Wob, (float*)d_out);
}

// Round 3
// 129.120 us; speedup vs baseline: 1.3628x; 1.1404x over previous
//
#include <hip/hip_runtime.h>

typedef unsigned int u32;
typedef unsigned short u16;
typedef unsigned long long u64;
typedef __attribute__((ext_vector_type(8))) short s16x8;
typedef __attribute__((ext_vector_type(8))) __bf16 bf16x8;
typedef __attribute__((ext_vector_type(4))) float f32x4;

#define WSMB (1ull << 20)

static __device__ __forceinline__ u16 f2bf(float f) {
  u32 u = __builtin_bit_cast(u32, f);
  return (u16)((u + 0x7fffu + ((u >> 16) & 1u)) >> 16);
}

// v_cvt_pk_bf16_f32: low16 = bf16(lo), high16 = bf16(hi)  (RNE)
static __device__ __forceinline__ u32 pkbf(float lo, float hi) {
  u32 r;
  asm("v_cvt_pk_bf16_f32 %0, %1, %2" : "=v"(r) : "v"(lo), "v"(hi));
  return r;
}

static __device__ __forceinline__ f32x4 mfma16x16(s16x8 a, s16x8 b, f32x4 c) {
  return __builtin_amdgcn_mfma_f32_16x16x32_bf16(
      __builtin_bit_cast(bf16x8, a), __builtin_bit_cast(bf16x8, b), c, 0, 0, 0);
}

#define GLOAD_LDS16(g, l)                                                      \
  __builtin_amdgcn_global_load_lds(                                            \
      (const __attribute__((address_space(1))) u32*)(const void*)(g),          \
      (__attribute__((address_space(3))) u32*)(void*)(l), 16, 0, 0)

// ---------------- fp32 -> bf16 converts (merged launches) ----------------
__global__ __launch_bounds__(256) void k_cvt3(const float* __restrict__ a,
                                              const float* __restrict__ b,
                                              const float* __restrict__ c,
                                              u16* __restrict__ oa,
                                              u16* __restrict__ ob,
                                              u16* __restrict__ oc) {
  const float* s;
  u16* d;
  if (blockIdx.y == 0) { s = a; d = oa; }
  else if (blockIdx.y == 1) { s = b; d = ob; }
  else { s = c; d = oc; }
  int i = (blockIdx.x * 256 + threadIdx.x) * 4;
  float4 v = *(const float4*)(s + i);
  u64 p = (u64)f2bf(v.x) | ((u64)f2bf(v.y) << 16) | ((u64)f2bf(v.z) << 32) |
          ((u64)f2bf(v.w) << 48);
  *(u64*)(d + i) = p;
}

__global__ __launch_bounds__(256) void k_cvt4(const float* __restrict__ a,
                                              const float* __restrict__ b,
                                              const float* __restrict__ c,
                                              const float* __restrict__ e,
                                              u16* __restrict__ oa,
                                              u16* __restrict__ ob,
                                              u16* __restrict__ oc,
                                              u16* __restrict__ oe) {
  const float* s;
  u16* d;
  if (blockIdx.y == 0) { s = a; d = oa; }
  else if (blockIdx.y == 1) { s = b; d = ob; }
  else if (blockIdx.y == 2) { s = c; d = oc; }
  else { s = e; d = oe; }
  int i = (blockIdx.x * 256 + threadIdx.x) * 4;
  float4 v = *(const float4*)(s + i);
  u64 p = (u64)f2bf(v.x) | ((u64)f2bf(v.y) << 16) | ((u64)f2bf(v.z) << 32) |
          ((u64)f2bf(v.w) << 48);
  *(u64*)(d + i) = p;
}

// ---------------- mask -> 64-bit row bitmasks ----------------
__global__ __launch_bounds__(256) void k_bits(const float* __restrict__ mask,
                                              u64* __restrict__ bits) {
  int w = threadIdx.x >> 6, l = threadIdx.x & 63;
  int r = blockIdx.x * 4 + w;  // r in [0, 4096) = b*1024+s
  float v = mask[(size_t)r * 64 + l];
  u64 bl = __ballot(v != 0.0f);
  if (l == 0) bits[r] = bl;
}

// ---------------- mask bit-matrix: MB[qg][kt] bit j = row qg visible key kt*64+j
__global__ __launch_bounds__(256) void k_mm(const u64* __restrict__ bits,
                                            u64* __restrict__ MB) {
  int wv = threadIdx.x >> 6, l = threadIdx.x & 63;
  int qg = blockIdx.x * 4 + wv;  // 0..4095
  u64 bq = bits[qg];
  const u64* bb = bits + (qg & ~1023);
  u64* out = MB + (size_t)qg * 16;
  for (int kt = 0; kt < 16; kt++) {
    u64 bk = bb[kt * 64 + l];
    u64 m = __ballot((bq & bk) != 0ull);
    if (l == 0) out[kt] = m;
  }
}

// ------- shared GEMM core: C[128x128] = A[128xK] * B[128xK]^T --------------
// acc[i][j][r]: A-row = amr + i*16 + lk*4 + r, B-row = bnr + j*16 + lr.
// Double-buffered (1 barrier/iter, loads overlap compute), XOR-swizzled LDS
// (byte ^= (row&6)<<3) with pre-swizzled global source (linear gload_lds dest).
static __device__ __forceinline__ void gemm_core(const u16* __restrict__ A,
                                                 const u16* __restrict__ Bw,
                                                 f32x4 (&acc)[4][4]) {
  __shared__ __attribute__((aligned(16))) u16 As[2][4096];
  __shared__ __attribute__((aligned(16))) u16 Bs[2][4096];
  const int t = threadIdx.x;
  const int l = t & 63, w = t >> 6, lr = l & 15, lk = l >> 4;
  const int amr = (w & 1) * 64, bnr = (w >> 1) * 64;
  const int c0 = t, c1 = t + 256;
  const int r0 = c0 >> 2, r1 = c1 >> 2;
  const int sw0 = ((c0 & 3) * 8) ^ ((r0 & 6) << 2);  // element offset in row
  const int sw1 = ((c1 & 3) * 8) ^ ((r1 & 6) << 2);
  const u16* Ag0 = A + (size_t)r0 * 1024 + sw0;
  const u16* Ag1 = A + (size_t)r1 * 1024 + sw1;
  const u16* Bg0 = Bw + (size_t)r0 * 1024 + sw0;
  const u16* Bg1 = Bw + (size_t)r1 * 1024 + sw1;
  const int aswz = (lk * 16) ^ ((lr & 6) << 3);  // byte offset in 64B row

  GLOAD_LDS16(Ag0, &As[0][c0 * 8]);
  GLOAD_LDS16(Ag1, &As[0][c1 * 8]);
  GLOAD_LDS16(Bg0, &Bs[0][c0 * 8]);
  GLOAD_LDS16(Bg1, &Bs[0][c1 * 8]);

  int cur = 0;
  for (int kt = 0; kt < 1024; kt += 32) {
    __syncthreads();  // drains cur loads + prev-iter LDS reads
    if (kt < 992) {
      const int nxt = cur ^ 1;
      GLOAD_LDS16(Ag0 + kt + 32, &As[nxt][c0 * 8]);
      GLOAD_LDS16(Ag1 + kt + 32, &As[nxt][c1 * 8]);
      GLOAD_LDS16(Bg0 + kt + 32, &Bs[nxt][c0 * 8]);
      GLOAD_LDS16(Bg1 + kt + 32, &Bs[nxt][c1 * 8]);
    }
    const char* Ac = (const char*)As[cur];
    const char* Bc = (const char*)Bs[cur];
    s16x8 af[4], bf[4];
#pragma unroll
    for (int i = 0; i < 4; i++)
      af[i] = *(const s16x8*)(Ac + (amr + i * 16 + lr) * 64 + aswz);
#pragma unroll
    for (int j = 0; j < 4; j++)
      bf[j] = *(const s16x8*)(Bc + (bnr + j * 16 + lr) * 64 + aswz);
    __builtin_amdgcn_s_setprio(1);
#pragma unroll
    for (int i = 0; i < 4; i++)
#pragma unroll
      for (int j = 0; j < 4; j++)
        acc[i][j] = mfma16x16(af[i], bf[j], acc[i][j]);
    __builtin_amdgcn_s_setprio(0);
    cur ^= 1;
  }
}

// ---------------- fused QKV projection ----------------
// Q/K: C^T orientation (rows=d, cols=s) -> packed b64 stores to [b,h][s][d].
// V:   C orientation (rows=s, cols=d) -> packed b64 stores to blocked
//      V4[b,h][s>>3][d][s&7].
__global__ __launch_bounds__(256) void k_qkv(
    const u16* __restrict__ Xq, const u16* __restrict__ Xk,
    const u16* __restrict__ Xv, const u16* __restrict__ Wqb,
    const u16* __restrict__ Wkb, const u16* __restrict__ Wvb,
    const float* __restrict__ bq, const float* __restrict__ bk,
    const float* __restrict__ bv, u16* __restrict__ Qo, u16* __restrict__ Ko,
    u16* __restrict__ V4) {
  const int bid0 = blockIdx.x;
  const int bid = (bid0 & 7) * 96 + (bid0 >> 3);  // XCD swizzle (768%8==0)
  const int proj = bid >> 8;
  const int rem = bid & 255;
  const int st = rem >> 3, dt = rem & 7;
  const u16* Xp = proj == 0 ? Xq : (proj == 1 ? Xk : Xv);
  const u16* Wp = proj == 0 ? Wqb : (proj == 1 ? Wkb : Wvb);
  const float* bias = proj == 0 ? bq : (proj == 1 ? bk : bv);
  const int t = threadIdx.x;
  const int l = t & 63, w = t >> 6, lr = l & 15, lk = l >> 4;
  const int amr = (w & 1) * 64, bnr = (w >> 1) * 64;
  f32x4 acc[4][4] = {};
  if (proj < 2) {
    gemm_core(Wp + (size_t)dt * 131072, Xp + (size_t)st * 131072, acc);
    u16* O = proj ? Ko : Qo;
#pragma unroll
    for (int i = 0; i < 4; i++) {
      const int d0 = dt * 128 + amr + i * 16 + lk * 4;
      const int h = d0 >> 6, dd0 = d0 & 63;
      const float4 b4 = *(const float4*)(bias + d0);
#pragma unroll
      for (int j = 0; j < 4; j++) {
        const int s = st * 128 + bnr + j * 16 + lr;
        const int b_ = s >> 10, si = s & 1023;
        u32 e0 = pkbf(acc[i][j][0] + b4.x, acc[i][j][1] + b4.y);
        u32 e1 = pkbf(acc[i][j][2] + b4.z, acc[i][j][3] + b4.w);
        *(u64*)(O + ((size_t)((b_ * 16 + h) * 1024 + si)) * 64 + dd0) =
            (u64)e0 | ((u64)e1 << 32);
      }
    }
  } else {
    gemm_core(Xp + (size_t)st * 131072, Wp + (size_t)dt * 131072, acc);
#pragma unroll
    for (int i = 0; i < 4; i++) {
      const int s0 = st * 128 + amr + i * 16 + lk * 4;
      const int b_ = s0 >> 10, si = s0 & 1023;
      const int sblk = si >> 3, soff = si & 7;
#pragma unroll
      for (int j = 0; j < 4; j++) {
        const int d = dt * 128 + bnr + j * 16 + lr;
        const int h = d >> 6, dd = d & 63;
        const float bb = bias[d];
        u32 e0 = pkbf(acc[i][j][0] + bb, acc[i][j][1] + bb);
        u32 e1 = pkbf(acc[i][j][2] + bb, acc[i][j][3] + bb);
        *(u64*)(V4 + (size_t)(b_ * 16 + h) * 65536 +
                (size_t)(sblk * 64 + dd) * 8 + soff) =
            (u64)e0 | ((u64)e1 << 32);
      }
    }
  }
}

// ---------------- output projection ----------------
__global__ __launch_bounds__(256) void k_oproj(const u16* __restrict__ Xb,
                                               const u16* __restrict__ Wob,
                                               float* __restrict__ Out) {
  const int bid0 = blockIdx.x;
  const int bid = (bid0 & 7) * 32 + (bid0 >> 3);  // XCD swizzle (256%8==0)
  const int mb = bid >> 3, nb = bid & 7;
  f32x4 acc[4][4] = {};
  gemm_core(Xb + (size_t)mb * 131072, Wob + (size_t)nb * 131072, acc);
  const int t = threadIdx.x;
  const int l = t & 63, w = t >> 6, lr = l & 15, lk = l >> 4;
  const int amr = (w & 1) * 64, bnr = (w >> 1) * 64;
#pragma unroll
  for (int i = 0; i < 4; i++)
#pragma unroll
    for (int j = 0; j < 4; j++)
#pragma unroll
      for (int r = 0; r < 4; r++) {
        const int m = mb * 128 + amr + i * 16 + lk * 4 + r;
        const int n = nb * 128 + bnr + j * 16 + lr;
        Out[(size_t)m * 1024 + n] = acc[i][j][r];
      }
}

// ---------------- flash attention (swapped QK^T, per-lane softmax) ---------
__global__ __launch_bounds__(256, 4) void k_attn(const u16* __restrict__ Qb,
                                                 const u16* __restrict__ Kb,
                                                 const u16* __restrict__ V4,
                                                 const u64* __restrict__ MB,
                                                 u16* __restrict__ xbuf) {
  __shared__ __attribute__((aligned(16))) u16 Ks[2][4096];
  __shared__ __attribute__((aligned(16))) u16 Vs[2][4096];
  __shared__ __attribute__((aligned(16))) u16 Ps[4][1024];
  const int t = threadIdx.x, l = t & 63, w = t >> 6, lr = l & 15, lk = l >> 4;
  const int bid = (blockIdx.x & 7) * 128 + (blockIdx.x >> 3);  // XCD swizzle
  const int qt = bid & 15, hb = bid >> 4;
  const int h = hb >> 2, b = hb & 3;
  const int s0 = qt * 64;
  const u16* Qhb = Qb + (size_t)(b * 16 + h) * 65536;
  const u16* Khb = Kb + (size_t)(b * 16 + h) * 65536;
  const u16* Vhb = V4 + (size_t)(b * 16 + h) * 65536;
  const int q = s0 + w * 16 + lr;  // this lane's q (output column)
  const u64* MBq = MB + ((size_t)b * 1024 + q) * 16;

  // Q fragments (B-operand): lane holds Q[q][d-slice lk*8..]
  s16x8 qf0 = *(const s16x8*)(Qhb + (size_t)q * 64 + lk * 8);
  s16x8 qf1 = *(const s16x8*)(Qhb + (size_t)q * 64 + 32 + lk * 8);

  f32x4 xa[4] = {};  // out^T: xa[nd][r] = O[d = nd*16+lk*4+r][q]
  float m_ = -__builtin_inff(), ls = 0.f;

  // staging geometry (pre-swizzled global source, linear LDS dest)
  const int ca = t, cb_ = t + 256;
  const int rA = ca >> 3, colA = (ca & 7) * 16;
  const int rB = cb_ >> 3, colB = (cb_ & 7) * 16;
  const int sA = colA ^ ((rA & 7) << 4);
  const int sB = colB ^ ((rB & 7) << 4);
  const u16* KgA = Khb + (size_t)rA * 64 + (sA >> 1);
  const u16* KgB = Khb + (size_t)rB * 64 + (sB >> 1);
  // V4 blocked layout: [sblk][d][8]; tile kt covers sblk kt*8..kt*8+7
  const u16* VgA = Vhb + (size_t)(sA >> 4) * 512 + rA * 8;
  const u16* VgB = Vhb + (size_t)(sB >> 4) * 512 + rB * 8;

  // prologue: stage tile 0 into buffer 0
  GLOAD_LDS16(KgA, &Ks[0][ca * 8]);
  GLOAD_LDS16(KgB, &Ks[0][cb_ * 8]);
  GLOAD_LDS16(VgA, &Vs[0][ca * 8]);
  GLOAD_LDS16(VgB, &Vs[0][cb_ * 8]);

  int cur = 0;
  for (int kt = 0; kt < 16; kt++) {
    __syncthreads();  // drains cur-tile loads (vmcnt0) + prior compute
    if (kt < 15) {    // prefetch next tile into the other buffer
      const int nxt = cur ^ 1;
      GLOAD_LDS16(KgA + (kt + 1) * 4096, &Ks[nxt][ca * 8]);
      GLOAD_LDS16(KgB + (kt + 1) * 4096, &Ks[nxt][cb_ * 8]);
      GLOAD_LDS16(VgA + (kt + 1) * 4096, &Vs[nxt][ca * 8]);
      GLOAD_LDS16(VgB + (kt + 1) * 4096, &Vs[nxt][cb_ * 8]);
    }
    const u16* Kc = Ks[cur];
    const u16* Vc = Vs[cur];
    const int kb = kt * 64;

    // swapped QK^T: z[nb] rows = keys, cols = q
    u64 mw = MBq[kt];
    u32 mlo = (u32)(mw >> (lk * 4));
    u32 mhi = (u32)(mw >> (lk * 4 + 32));
    float p[4][4];
#pragma unroll
    for (int nb = 0; nb < 4; nb++) {
      const int krow = nb * 16 + lr;
      const int sw = (krow & 7) << 4;
      s16x8 k0 = *(const s16x8*)((const char*)Kc + krow * 128 + ((lk * 16) ^ sw));
      s16x8 k1 =
          *(const s16x8*)((const char*)Kc + krow * 128 + ((64 + lk * 16) ^ sw));
      f32x4 z = {};
      __builtin_amdgcn_s_setprio(1);
      z = mfma16x16(k0, qf0, z);
      z = mfma16x16(k1, qf1, z);
      __builtin_amdgcn_s_setprio(0);
#pragma unroll
      for (int r = 0; r < 4; r++) p[nb][r] = z[r] * 0.125f;
    }
    (void)kb;

    // per-lane online softmax (lane owns q; 16 keys in-register, 4 lk groups)
    float tm = fmaxf(fmaxf(p[0][0], p[0][1]), fmaxf(p[0][2], p[0][3]));
#pragma unroll
    for (int nb = 1; nb < 4; nb++)
      tm = fmaxf(tm,
                 fmaxf(fmaxf(p[nb][0], p[nb][1]), fmaxf(p[nb][2], p[nb][3])));
    tm = fmaxf(tm, __shfl_xor(tm, 16));
    tm = fmaxf(tm, __shfl_xor(tm, 32));
    const float mn = fmaxf(m_, tm);
    const float scl = __expf(m_ - mn);
    m_ = mn;
    float ts = 0.f;
#pragma unroll
    for (int nb = 0; nb < 4; nb++) {
      const u32 mword = (nb & 2) ? mhi : mlo;
#pragma unroll
      for (int r = 0; r < 4; r++) {
        float e = __expf(p[nb][r] - mn);
        e = ((mword >> ((nb & 1) * 16 + r)) & 1u) ? e : 0.f;
        p[nb][r] = e;
        ts += e;
      }
    }
    ts += __shfl_xor(ts, 16);
    ts += __shfl_xor(ts, 32);
    ls = ls * scl + ts;
#pragma unroll
    for (int nd = 0; nd < 4; nd++) xa[nd] *= scl;

    // P -> LDS (row = q, 64 keys), swizzled; hw cvt_pk packs pairs
    char* Pw = (char*)&Ps[w][0];
#pragma unroll
    for (int nb = 0; nb < 4; nb++) {
      u32 w0 = pkbf(p[nb][0], p[nb][1]);
      u32 w1 = pkbf(p[nb][2], p[nb][3]);
      *(u64*)(Pw + lr * 128 + ((nb * 32 + lk * 8) ^ ((lr & 7) << 4))) =
          (u64)w0 | ((u64)w1 << 32);
    }
    const int sw2 = (lr & 7) << 4;
    s16x8 pb0 = *(const s16x8*)(Pw + lr * 128 + ((lk * 16) ^ sw2));
    s16x8 pb1 = *(const s16x8*)(Pw + lr * 128 + ((64 + lk * 16) ^ sw2));

    // PV: out^T = V^T * P  (A = V^T rows d, B = P cols q)
    __builtin_amdgcn_s_setprio(1);
#pragma unroll
    for (int nd = 0; nd < 4; nd++) {
      const int vrow = nd * 16 + lr;
      const int vsw = (vrow & 7) << 4;
      s16x8 v0 = *(const s16x8*)((const char*)Vc + vrow * 128 + ((lk * 16) ^ vsw));
      s16x8 v1 =
          *(const s16x8*)((const char*)Vc + vrow * 128 + ((64 + lk * 16) ^ vsw));
      xa[nd] = mfma16x16(v0, pb0, xa[nd]);
      xa[nd] = mfma16x16(v1, pb1, xa[nd]);
    }
    __builtin_amdgcn_s_setprio(0);
    cur ^= 1;
  }

  // epilogue: normalize + write in the reference's mixed reshape layout
  const float inv = 1.0f / ls;
  const size_t rowb = (size_t)b * 1048576 + (size_t)(h * 64 + (q >> 4)) * 1024 +
                      (size_t)(q & 15) * 64;
#pragma unroll
  for (int nd = 0; nd < 4; nd++) {
    u32 e0 = pkbf(xa[nd][0] * inv, xa[nd][1] * inv);
    u32 e1 = pkbf(xa[nd][2] * inv, xa[nd][3] * inv);
    *(u64*)(xbuf + rowb + nd * 16 + lk * 4) = (u64)e0 | ((u64)e1 << 32);
  }
}

extern "C" void kernel_launch(void* const* d_in, const int* in_sizes, int n_in,
                              void* d_out, int out_size, void* d_ws,
                              size_t ws_size, hipStream_t stream) {
  const float* query = (const float*)d_in[0];
  const float* key_ = (const float*)d_in[1];
  const float* value = (const float*)d_in[2];
  const float* mask = (const float*)d_in[3];
  const float* bq = (const float*)d_in[5];
  const float* bk = (const float*)d_in[7];
  const float* bv = (const float*)d_in[9];
  const float* Wq = (const float*)d_in[4];
  const float* Wk = (const float*)d_in[6];
  const float* Wv = (const float*)d_in[8];
  const float* Wo = (const float*)d_in[10];

  char* ws = (char*)d_ws;
  u16* Xq = (u16*)(ws + 0 * WSMB);   // reused as xbuf after QKV GEMM
  u16* Xk = (u16*)(ws + 8 * WSMB);   // reused as MB after QKV GEMM
  u16* Xv = (u16*)(ws + 16 * WSMB);
  u16* Wqb = (u16*)(ws + 24 * WSMB);
  u16* Wkb = (u16*)(ws + 26 * WSMB);
  u16* Wvb = (u16*)(ws + 28 * WSMB);
  u16* Wob = (u16*)(ws + 30 * WSMB);
  u16* Qb = (u16*)(ws + 32 * WSMB);
  u16* Kb = (u16*)(ws + 40 * WSMB);
  u16* V4 = (u16*)(ws + 48 * WSMB);
  u64* bits = (u64*)(ws + 56 * WSMB);
  u64* MBm = (u64*)(ws + 8 * WSMB);  // 512 KB, overlaps dead Xk
  u16* xbuf = Xq;

  k_cvt3<<<dim3(4096, 3), 256, 0, stream>>>(query, key_, value, Xq, Xk, Xv);
  k_cvt4<<<dim3(1024, 4), 256, 0, stream>>>(Wq, Wk, Wv, Wo, Wqb, Wkb, Wvb, Wob);
  k_bits<<<1024, 256, 0, stream>>>(mask, bits);
  k_qkv<<<768, 256, 0, stream>>>(Xq, Xk, Xv, Wqb, Wkb, Wvb, bq, bk, bv, Qb, Kb,
                                 V4);
  k_mm<<<1024, 256, 0, stream>>>(bits, MBm);
  k_attn<<<1024, 256, 0, stream>>>(Qb, Kb, V4, MBm, xbuf);
  k_oproj<<<256, 256, 0, stream>>>(xbuf, Wob, (float*)d_out);
}

// Round 4
// 127.761 us; speedup vs baseline: 1.3773x; 1.0106x over previous
//
#include <hip/hip_runtime.h>

typedef unsigned int u32;
typedef unsigned short u16;
typedef unsigned long long u64;
typedef __attribute__((ext_vector_type(8))) short s16x8;
typedef __attribute__((ext_vector_type(8))) __bf16 bf16x8;
typedef __attribute__((ext_vector_type(4))) float f32x4;

#define WSMB (1ull << 20)
#define QSC 0.18033688011112042f  // log2(e)/8, folded into Q projection

static __device__ __forceinline__ u16 f2bf(float f) {
  u32 u = __builtin_bit_cast(u32, f);
  return (u16)((u + 0x7fffu + ((u >> 16) & 1u)) >> 16);
}

// v_cvt_pk_bf16_f32: low16 = bf16(lo), high16 = bf16(hi)  (RNE)
static __device__ __forceinline__ u32 pkbf(float lo, float hi) {
  u32 r;
  asm("v_cvt_pk_bf16_f32 %0, %1, %2" : "=v"(r) : "v"(lo), "v"(hi));
  return r;
}

// native exp2
static __device__ __forceinline__ float ex2(float x) {
  float r;
  asm("v_exp_f32 %0, %1" : "=v"(r) : "v"(x));
  return r;
}

static __device__ __forceinline__ f32x4 mfma16x16(s16x8 a, s16x8 b, f32x4 c) {
  return __builtin_amdgcn_mfma_f32_16x16x32_bf16(
      __builtin_bit_cast(bf16x8, a), __builtin_bit_cast(bf16x8, b), c, 0, 0, 0);
}

#define GLOAD_LDS16(g, l)                                                      \
  __builtin_amdgcn_global_load_lds(                                            \
      (const __attribute__((address_space(1))) u32*)(const void*)(g),          \
      (__attribute__((address_space(3))) u32*)(void*)(l), 16, 0, 0)

// ---------------- fp32 -> bf16 converts (merged launches) ----------------
__global__ __launch_bounds__(256) void k_cvt3(const float* __restrict__ a,
                                              const float* __restrict__ b,
                                              const float* __restrict__ c,
                                              u16* __restrict__ oa,
                                              u16* __restrict__ ob,
                                              u16* __restrict__ oc) {
  const float* s;
  u16* d;
  if (blockIdx.y == 0) { s = a; d = oa; }
  else if (blockIdx.y == 1) { s = b; d = ob; }
  else { s = c; d = oc; }
  int i = (blockIdx.x * 256 + threadIdx.x) * 4;
  float4 v = *(const float4*)(s + i);
  u64 p = (u64)f2bf(v.x) | ((u64)f2bf(v.y) << 16) | ((u64)f2bf(v.z) << 32) |
          ((u64)f2bf(v.w) << 48);
  *(u64*)(d + i) = p;
}

__global__ __launch_bounds__(256) void k_cvt4(const float* __restrict__ a,
                                              const float* __restrict__ b,
                                              const float* __restrict__ c,
                                              const float* __restrict__ e,
                                              u16* __restrict__ oa,
                                              u16* __restrict__ ob,
                                              u16* __restrict__ oc,
                                              u16* __restrict__ oe) {
  const float* s;
  u16* d;
  if (blockIdx.y == 0) { s = a; d = oa; }
  else if (blockIdx.y == 1) { s = b; d = ob; }
  else if (blockIdx.y == 2) { s = c; d = oc; }
  else { s = e; d = oe; }
  int i = (blockIdx.x * 256 + threadIdx.x) * 4;
  float4 v = *(const float4*)(s + i);
  u64 p = (u64)f2bf(v.x) | ((u64)f2bf(v.y) << 16) | ((u64)f2bf(v.z) << 32) |
          ((u64)f2bf(v.w) << 48);
  *(u64*)(d + i) = p;
}

// ---------------- mask -> 64-bit row bitmasks ----------------
__global__ __launch_bounds__(256) void k_bits(const float* __restrict__ mask,
                                              u64* __restrict__ bits) {
  int w = threadIdx.x >> 6, l = threadIdx.x & 63;
  int r = blockIdx.x * 4 + w;  // r in [0, 4096) = b*1024+s
  float v = mask[(size_t)r * 64 + l];
  u64 bl = __ballot(v != 0.0f);
  if (l == 0) bits[r] = bl;
}

// ---------------- mask bit-matrix: MB[qg][kt] bit j = row qg visible key kt*64+j
__global__ __launch_bounds__(256) void k_mm(const u64* __restrict__ bits,
                                            u64* __restrict__ MB) {
  int wv = threadIdx.x >> 6, l = threadIdx.x & 63;
  int qg = blockIdx.x * 4 + wv;  // 0..4095
  u64 bq = bits[qg];
  const u64* bb = bits + (qg & ~1023);
  u64* out = MB + (size_t)qg * 16;
  for (int kt = 0; kt < 16; kt++) {
    u64 bk = bb[kt * 64 + l];
    u64 m = __ballot((bq & bk) != 0ull);
    if (l == 0) out[kt] = m;
  }
}

// ------- shared GEMM core: C[128x128] = A[128xK] * B[128xK]^T --------------
static __device__ __forceinline__ void gemm_core(const u16* __restrict__ A,
                                                 const u16* __restrict__ Bw,
                                                 f32x4 (&acc)[4][4]) {
  __shared__ __attribute__((aligned(16))) u16 As[2][4096];
  __shared__ __attribute__((aligned(16))) u16 Bs[2][4096];
  const int t = threadIdx.x;
  const int l = t & 63, w = t >> 6, lr = l & 15, lk = l >> 4;
  const int amr = (w & 1) * 64, bnr = (w >> 1) * 64;
  const int c0 = t, c1 = t + 256;
  const int r0 = c0 >> 2, r1 = c1 >> 2;
  const int sw0 = ((c0 & 3) * 8) ^ ((r0 & 6) << 2);  // element offset in row
  const int sw1 = ((c1 & 3) * 8) ^ ((r1 & 6) << 2);
  const u16* Ag0 = A + (size_t)r0 * 1024 + sw0;
  const u16* Ag1 = A + (size_t)r1 * 1024 + sw1;
  const u16* Bg0 = Bw + (size_t)r0 * 1024 + sw0;
  const u16* Bg1 = Bw + (size_t)r1 * 1024 + sw1;
  const int aswz = (lk * 16) ^ ((lr & 6) << 3);  // byte offset in 64B row

  GLOAD_LDS16(Ag0, &As[0][c0 * 8]);
  GLOAD_LDS16(Ag1, &As[0][c1 * 8]);
  GLOAD_LDS16(Bg0, &Bs[0][c0 * 8]);
  GLOAD_LDS16(Bg1, &Bs[0][c1 * 8]);

  int cur = 0;
  for (int kt = 0; kt < 1024; kt += 32) {
    __syncthreads();  // drains cur loads + prev-iter LDS reads
    if (kt < 992) {
      const int nxt = cur ^ 1;
      GLOAD_LDS16(Ag0 + kt + 32, &As[nxt][c0 * 8]);
      GLOAD_LDS16(Ag1 + kt + 32, &As[nxt][c1 * 8]);
      GLOAD_LDS16(Bg0 + kt + 32, &Bs[nxt][c0 * 8]);
      GLOAD_LDS16(Bg1 + kt + 32, &Bs[nxt][c1 * 8]);
    }
    const char* Ac = (const char*)As[cur];
    const char* Bc = (const char*)Bs[cur];
    s16x8 af[4], bf[4];
#pragma unroll
    for (int i = 0; i < 4; i++)
      af[i] = *(const s16x8*)(Ac + (amr + i * 16 + lr) * 64 + aswz);
#pragma unroll
    for (int j = 0; j < 4; j++)
      bf[j] = *(const s16x8*)(Bc + (bnr + j * 16 + lr) * 64 + aswz);
    __builtin_amdgcn_s_setprio(1);
#pragma unroll
    for (int i = 0; i < 4; i++)
#pragma unroll
      for (int j = 0; j < 4; j++)
        acc[i][j] = mfma16x16(af[i], bf[j], acc[i][j]);
    __builtin_amdgcn_s_setprio(0);
    cur ^= 1;
  }
}

// ---------------- fused QKV projection ----------------
// Q/K: C^T orientation (rows=d, cols=s) -> packed b64 stores to [b,h][s][d].
// Q additionally scaled by QSC = log2(e)/8 (attn uses exp2 domain).
// V:   C orientation -> blocked V4[b,h][s>>3][d][s&7].
__global__ __launch_bounds__(256) void k_qkv(
    const u16* __restrict__ Xq, const u16* __restrict__ Xk,
    const u16* __restrict__ Xv, const u16* __restrict__ Wqb,
    const u16* __restrict__ Wkb, const u16* __restrict__ Wvb,
    const float* __restrict__ bq, const float* __restrict__ bk,
    const float* __restrict__ bv, u16* __restrict__ Qo, u16* __restrict__ Ko,
    u16* __restrict__ V4) {
  const int bid0 = blockIdx.x;
  const int bid = (bid0 & 7) * 96 + (bid0 >> 3);  // XCD swizzle (768%8==0)
  const int proj = bid >> 8;
  const int rem = bid & 255;
  const int st = rem >> 3, dt = rem & 7;
  const u16* Xp = proj == 0 ? Xq : (proj == 1 ? Xk : Xv);
  const u16* Wp = proj == 0 ? Wqb : (proj == 1 ? Wkb : Wvb);
  const float* bias = proj == 0 ? bq : (proj == 1 ? bk : bv);
  const int t = threadIdx.x;
  const int l = t & 63, w = t >> 6, lr = l & 15, lk = l >> 4;
  const int amr = (w & 1) * 64, bnr = (w >> 1) * 64;
  f32x4 acc[4][4] = {};
  if (proj < 2) {
    const float sc = proj == 0 ? QSC : 1.0f;
    gemm_core(Wp + (size_t)dt * 131072, Xp + (size_t)st * 131072, acc);
    u16* O = proj ? Ko : Qo;
#pragma unroll
    for (int i = 0; i < 4; i++) {
      const int d0 = dt * 128 + amr + i * 16 + lk * 4;
      const int h = d0 >> 6, dd0 = d0 & 63;
      const float4 b4 = *(const float4*)(bias + d0);
#pragma unroll
      for (int j = 0; j < 4; j++) {
        const int s = st * 128 + bnr + j * 16 + lr;
        const int b_ = s >> 10, si = s & 1023;
        u32 e0 = pkbf((acc[i][j][0] + b4.x) * sc, (acc[i][j][1] + b4.y) * sc);
        u32 e1 = pkbf((acc[i][j][2] + b4.z) * sc, (acc[i][j][3] + b4.w) * sc);
        *(u64*)(O + ((size_t)((b_ * 16 + h) * 1024 + si)) * 64 + dd0) =
            (u64)e0 | ((u64)e1 << 32);
      }
    }
  } else {
    gemm_core(Xp + (size_t)st * 131072, Wp + (size_t)dt * 131072, acc);
#pragma unroll
    for (int i = 0; i < 4; i++) {
      const int s0 = st * 128 + amr + i * 16 + lk * 4;
      const int b_ = s0 >> 10, si = s0 & 1023;
      const int sblk = si >> 3, soff = si & 7;
#pragma unroll
      for (int j = 0; j < 4; j++) {
        const int d = dt * 128 + bnr + j * 16 + lr;
        const int h = d >> 6, dd = d & 63;
        const float bb = bias[d];
        u32 e0 = pkbf(acc[i][j][0] + bb, acc[i][j][1] + bb);
        u32 e1 = pkbf(acc[i][j][2] + bb, acc[i][j][3] + bb);
        *(u64*)(V4 + (size_t)(b_ * 16 + h) * 65536 +
                (size_t)(sblk * 64 + dd) * 8 + soff) =
            (u64)e0 | ((u64)e1 << 32);
      }
    }
  }
}

// ---------------- output projection ----------------
__global__ __launch_bounds__(256) void k_oproj(const u16* __restrict__ Xb,
                                               const u16* __restrict__ Wob,
                                               float* __restrict__ Out) {
  const int bid0 = blockIdx.x;
  const int bid = (bid0 & 7) * 32 + (bid0 >> 3);  // XCD swizzle (256%8==0)
  const int mb = bid >> 3, nb = bid & 7;
  f32x4 acc[4][4] = {};
  gemm_core(Xb + (size_t)mb * 131072, Wob + (size_t)nb * 131072, acc);
  const int t = threadIdx.x;
  const int l = t & 63, w = t >> 6, lr = l & 15, lk = l >> 4;
  const int amr = (w & 1) * 64, bnr = (w >> 1) * 64;
#pragma unroll
  for (int i = 0; i < 4; i++)
#pragma unroll
    for (int j = 0; j < 4; j++)
#pragma unroll
      for (int r = 0; r < 4; r++) {
        const int m = mb * 128 + amr + i * 16 + lk * 4 + r;
        const int n = nb * 128 + bnr + j * 16 + lr;
        Out[(size_t)m * 1024 + n] = acc[i][j][r];
      }
}

// ---- per-q-group online softmax (exp2 domain, defer-max, mask-zeroing) ----
static __device__ __forceinline__ void softmax_g(float (&p)[4][4], u64 mw,
                                                 int lk, float& m_, float& ls,
                                                 f32x4 (&xa)[4]) {
  const u32 mlo = (u32)(mw >> (lk * 4));
  const u32 mhi = (u32)(mw >> (lk * 4 + 32));
  float tm = fmaxf(fmaxf(p[0][0], p[0][1]), fmaxf(p[0][2], p[0][3]));
#pragma unroll
  for (int nb = 1; nb < 4; nb++)
    tm = fmaxf(tm, fmaxf(fmaxf(p[nb][0], p[nb][1]), fmaxf(p[nb][2], p[nb][3])));
  tm = fmaxf(tm, __shfl_xor(tm, 16));
  tm = fmaxf(tm, __shfl_xor(tm, 32));
  if (!__all(tm <= m_ + 8.0f)) {  // defer-max: P bounded by 2^8, bf16-safe
    const float mn = fmaxf(m_, tm);
    const float scl = ex2(m_ - mn);
    m_ = mn;
    ls *= scl;
#pragma unroll
    for (int nd = 0; nd < 4; nd++) xa[nd] *= scl;
  }
  float ts = 0.f;
#pragma unroll
  for (int nb = 0; nb < 4; nb++) {
    const u32 mword = (nb & 2) ? mhi : mlo;
#pragma unroll
    for (int r = 0; r < 4; r++) {
      float e = ex2(p[nb][r] - m_);
      e = ((mword >> ((nb & 1) * 16 + r)) & 1u) ? e : 0.f;
      p[nb][r] = e;
      ts += e;
    }
  }
  ts += __shfl_xor(ts, 16);
  ts += __shfl_xor(ts, 32);
  ls += ts;
}

// ---------------- flash attention: 32 q per wave, 128 q per block ----------
__global__ __launch_bounds__(256, 2) void k_attn(const u16* __restrict__ Qb,
                                                 const u16* __restrict__ Kb,
                                                 const u16* __restrict__ V4,
                                                 const u64* __restrict__ MB,
                                                 u16* __restrict__ xbuf) {
  __shared__ __attribute__((aligned(16))) u16 Ks[2][4096];
  __shared__ __attribute__((aligned(16))) u16 Vs[2][4096];
  __shared__ __attribute__((aligned(16))) u16 Ps[4][2048];
  const int t = threadIdx.x, l = t & 63, w = t >> 6, lr = l & 15, lk = l >> 4;
  const int bid = (blockIdx.x & 7) * 64 + (blockIdx.x >> 3);  // XCD swizzle
  const int qt = bid & 7, hb = bid >> 3;
  const int h = hb >> 2, b = hb & 3;
  const int s0 = qt * 128;
  const u16* Qhb = Qb + (size_t)(b * 16 + h) * 65536;
  const u16* Khb = Kb + (size_t)(b * 16 + h) * 65536;
  const u16* Vhb = V4 + (size_t)(b * 16 + h) * 65536;
  const int qA = s0 + w * 32 + lr, qB = qA + 16;
  const u64* MBA = MB + ((size_t)b * 1024 + qA) * 16;
  const u64* MBB = MB + ((size_t)b * 1024 + qB) * 16;

  // Q fragments (B-operand), Q pre-scaled by log2(e)/8 in projection
  s16x8 qfA0 = *(const s16x8*)(Qhb + (size_t)qA * 64 + lk * 8);
  s16x8 qfA1 = *(const s16x8*)(Qhb + (size_t)qA * 64 + 32 + lk * 8);
  s16x8 qfB0 = *(const s16x8*)(Qhb + (size_t)qB * 64 + lk * 8);
  s16x8 qfB1 = *(const s16x8*)(Qhb + (size_t)qB * 64 + 32 + lk * 8);

  f32x4 xaA[4] = {}, xaB[4] = {};
  float mA = -__builtin_inff(), lsA = 0.f;
  float mB = -__builtin_inff(), lsB = 0.f;

  // staging geometry (pre-swizzled global source, linear LDS dest)
  const int ca = t, cb_ = t + 256;
  const int rA = ca >> 3, colA = (ca & 7) * 16;
  const int rB = cb_ >> 3, colB = (cb_ & 7) * 16;
  const int sA = colA ^ ((rA & 7) << 4);
  const int sB = colB ^ ((rB & 7) << 4);
  const u16* KgA = Khb + (size_t)rA * 64 + (sA >> 1);
  const u16* KgB = Khb + (size_t)rB * 64 + (sB >> 1);
  const u16* VgA = Vhb + (size_t)(sA >> 4) * 512 + rA * 8;
  const u16* VgB = Vhb + (size_t)(sB >> 4) * 512 + rB * 8;

  // prologue: stage tile 0; load tile-0 mask words
  GLOAD_LDS16(KgA, &Ks[0][ca * 8]);
  GLOAD_LDS16(KgB, &Ks[0][cb_ * 8]);
  GLOAD_LDS16(VgA, &Vs[0][ca * 8]);
  GLOAD_LDS16(VgB, &Vs[0][cb_ * 8]);
  u64 mwA = MBA[0], mwB = MBB[0];

  int cur = 0;
  for (int kt = 0; kt < 16; kt++) {
    __syncthreads();  // drains cur-tile loads + prior compute
    if (kt < 15) {    // prefetch next tile into the other buffer
      const int nxt = cur ^ 1;
      GLOAD_LDS16(KgA + (kt + 1) * 4096, &Ks[nxt][ca * 8]);
      GLOAD_LDS16(KgB + (kt + 1) * 4096, &Ks[nxt][cb_ * 8]);
      GLOAD_LDS16(VgA + (kt + 1) * 4096, &Vs[nxt][ca * 8]);
      GLOAD_LDS16(VgB + (kt + 1) * 4096, &Vs[nxt][cb_ * 8]);
    }
    const int ktn = (kt + 1) & 15;
    const u64 nwA = MBA[ktn], nwB = MBB[ktn];  // prefetch mask words
    const u16* Kc = Ks[cur];
    const u16* Vc = Vs[cur];

    // swapped QK^T: rows = keys, cols = q; both q-groups share K fragments
    float pA[4][4], pB[4][4];
#pragma unroll
    for (int nb = 0; nb < 4; nb++) {
      const int krow = nb * 16 + lr;
      const int sw = (krow & 7) << 4;
      s16x8 k0 = *(const s16x8*)((const char*)Kc + krow * 128 + ((lk * 16) ^ sw));
      s16x8 k1 =
          *(const s16x8*)((const char*)Kc + krow * 128 + ((64 + lk * 16) ^ sw));
      f32x4 zA = {}, zB = {};
      __builtin_amdgcn_s_setprio(1);
      zA = mfma16x16(k0, qfA0, zA);
      zA = mfma16x16(k1, qfA1, zA);
      zB = mfma16x16(k0, qfB0, zB);
      zB = mfma16x16(k1, qfB1, zB);
      __builtin_amdgcn_s_setprio(0);
#pragma unroll
      for (int r = 0; r < 4; r++) {
        pA[nb][r] = zA[r];
        pB[nb][r] = zB[r];
      }
    }

    softmax_g(pA, mwA, lk, mA, lsA, xaA);
    softmax_g(pB, mwB, lk, mB, lsB, xaB);

    // P -> per-wave LDS (rows 0-15 = group A, 16-31 = group B), swizzled
    char* Pw = (char*)&Ps[w][0];
#pragma unroll
    for (int nb = 0; nb < 4; nb++) {
      const int co = (nb * 32 + lk * 8) ^ ((lr & 7) << 4);
      u32 a0 = pkbf(pA[nb][0], pA[nb][1]);
      u32 a1 = pkbf(pA[nb][2], pA[nb][3]);
      *(u64*)(Pw + lr * 128 + co) = (u64)a0 | ((u64)a1 << 32);
      u32 b0 = pkbf(pB[nb][0], pB[nb][1]);
      u32 b1 = pkbf(pB[nb][2], pB[nb][3]);
      *(u64*)(Pw + (16 + lr) * 128 + co) = (u64)b0 | ((u64)b1 << 32);
    }
    const int sw2 = (lr & 7) << 4;
    s16x8 pa0 = *(const s16x8*)(Pw + lr * 128 + ((lk * 16) ^ sw2));
    s16x8 pa1 = *(const s16x8*)(Pw + lr * 128 + ((64 + lk * 16) ^ sw2));
    s16x8 pb0 = *(const s16x8*)(Pw + (16 + lr) * 128 + ((lk * 16) ^ sw2));
    s16x8 pb1 = *(const s16x8*)(Pw + (16 + lr) * 128 + ((64 + lk * 16) ^ sw2));

    // PV: out^T = V^T * P; V fragments shared by both q-groups
    __builtin_amdgcn_s_setprio(1);
#pragma unroll
    for (int nd = 0; nd < 4; nd++) {
      const int vrow = nd * 16 + lr;
      const int vsw = (vrow & 7) << 4;
      s16x8 v0 = *(const s16x8*)((const char*)Vc + vrow * 128 + ((lk * 16) ^ vsw));
      s16x8 v1 =
          *(const s16x8*)((const char*)Vc + vrow * 128 + ((64 + lk * 16) ^ vsw));
      xaA[nd] = mfma16x16(v0, pa0, xaA[nd]);
      xaA[nd] = mfma16x16(v1, pa1, xaA[nd]);
      xaB[nd] = mfma16x16(v0, pb0, xaB[nd]);
      xaB[nd] = mfma16x16(v1, pb1, xaB[nd]);
    }
    __builtin_amdgcn_s_setprio(0);
    mwA = nwA;
    mwB = nwB;
    cur ^= 1;
  }

  // epilogue: normalize + write in the reference's mixed reshape layout
  const float invA = 1.0f / lsA, invB = 1.0f / lsB;
  const size_t rbA = (size_t)b * 1048576 + (size_t)(h * 64 + (qA >> 4)) * 1024 +
                     (size_t)(qA & 15) * 64;
  const size_t rbB = (size_t)b * 1048576 + (size_t)(h * 64 + (qB >> 4)) * 1024 +
                     (size_t)(qB & 15) * 64;
#pragma unroll
  for (int nd = 0; nd < 4; nd++) {
    u32 a0 = pkbf(xaA[nd][0] * invA, xaA[nd][1] * invA);
    u32 a1 = pkbf(xaA[nd][2] * invA, xaA[nd][3] * invA);
    *(u64*)(xbuf + rbA + nd * 16 + lk * 4) = (u64)a0 | ((u64)a1 << 32);
    u32 b0 = pkbf(xaB[nd][0] * invB, xaB[nd][1] * invB);
    u32 b1 = pkbf(xaB[nd][2] * invB, xaB[nd][3] * invB);
    *(u64*)(xbuf + rbB + nd * 16 + lk * 4) = (u64)b0 | ((u64)b1 << 32);
  }
}

extern "C" void kernel_launch(void* const* d_in, const int* in_sizes, int n_in,
                              void* d_out, int out_size, void* d_ws,
                              size_t ws_size, hipStream_t stream) {
  const float* query = (const float*)d_in[0];
  const float* key_ = (const float*)d_in[1];
  const float* value = (const float*)d_in[2];
  const float* mask = (const float*)d_in[3];
  const float* bq = (const float*)d_in[5];
  const float* bk = (const float*)d_in[7];
  const float* bv = (const float*)d_in[9];
  const float* Wq = (const float*)d_in[4];
  const float* Wk = (const float*)d_in[6];
  const float* Wv = (const float*)d_in[8];
  const float* Wo = (const float*)d_in[10];

  char* ws = (char*)d_ws;
  u16* Xq = (u16*)(ws + 0 * WSMB);   // reused as xbuf after QKV GEMM
  u16* Xk = (u16*)(ws + 8 * WSMB);   // reused as MB after QKV GEMM
  u16* Xv = (u16*)(ws + 16 * WSMB);
  u16* Wqb = (u16*)(ws + 24 * WSMB);
  u16* Wkb = (u16*)(ws + 26 * WSMB);
  u16* Wvb = (u16*)(ws + 28 * WSMB);
  u16* Wob = (u16*)(ws + 30 * WSMB);
  u16* Qb = (u16*)(ws + 32 * WSMB);
  u16* Kb = (u16*)(ws + 40 * WSMB);
  u16* V4 = (u16*)(ws + 48 * WSMB);
  u64* bits = (u64*)(ws + 56 * WSMB);
  u64* MBm = (u64*)(ws + 8 * WSMB);  // 512 KB, overlaps dead Xk
  u16* xbuf = Xq;

  k_cvt3<<<dim3(4096, 3), 256, 0, stream>>>(query, key_, value, Xq, Xk, Xv);
  k_cvt4<<<dim3(1024, 4), 256, 0, stream>>>(Wq, Wk, Wv, Wo, Wqb, Wkb, Wvb, Wob);
  k_bits<<<1024, 256, 0, stream>>>(mask, bits);
  k_qkv<<<768, 256, 0, stream>>>(Xq, Xk, Xv, Wqb, Wkb, Wvb, bq, bk, bv, Qb, Kb,
                                 V4);
  k_mm<<<1024, 256, 0, stream>>>(bits, MBm);
  k_attn<<<512, 256, 0, stream>>>(Qb, Kb, V4, MBm, xbuf);
  k_oproj<<<256, 256, 0, stream>>>(xbuf, Wob, (float*)d_out);
}

// Round 7
// 119.029 us; speedup vs baseline: 1.4783x; 1.0734x over previous
//
#include <hip/hip_runtime.h>

typedef unsigned int u32;
typedef unsigned short u16;
typedef unsigned long long u64;
typedef __attribute__((ext_vector_type(8))) short s16x8;
typedef __attribute__((ext_vector_type(8))) __bf16 bf16x8;
typedef __attribute__((ext_vector_type(4))) float f32x4;
typedef __attribute__((ext_vector_type(16))) float f32x16;
typedef __attribute__((ext_vector_type(4))) u32 u32x4;

#define WSMB (1ull << 20)
#define QSC 0.18033688011112042f  // log2(e)/8, folded into Q projection

static __device__ __forceinline__ u16 f2bf(float f) {
  u32 u = __builtin_bit_cast(u32, f);
  return (u16)((u + 0x7fffu + ((u >> 16) & 1u)) >> 16);
}

// v_cvt_pk_bf16_f32: low16 = bf16(lo), high16 = bf16(hi)  (RNE)
static __device__ __forceinline__ u32 pkbf(float lo, float hi) {
  u32 r;
  asm("v_cvt_pk_bf16_f32 %0, %1, %2" : "=v"(r) : "v"(lo), "v"(hi));
  return r;
}

// native exp2
static __device__ __forceinline__ float ex2(float x) {
  float r;
  asm("v_exp_f32 %0, %1" : "=v"(r) : "v"(x));
  return r;
}

static __device__ __forceinline__ f32x4 mfma16x16(s16x8 a, s16x8 b, f32x4 c) {
  return __builtin_amdgcn_mfma_f32_16x16x32_bf16(
      __builtin_bit_cast(bf16x8, a), __builtin_bit_cast(bf16x8, b), c, 0, 0, 0);
}

static __device__ __forceinline__ f32x16 mfma32x32(s16x8 a, s16x8 b, f32x16 c) {
  return __builtin_amdgcn_mfma_f32_32x32x16_bf16(
      __builtin_bit_cast(bf16x8, a), __builtin_bit_cast(bf16x8, b), c, 0, 0, 0);
}

#define GLOAD_LDS16(g, l)                                                      \
  __builtin_amdgcn_global_load_lds(                                            \
      (const __attribute__((address_space(1))) u32*)(const void*)(g),          \
      (__attribute__((address_space(3))) u32*)(void*)(l), 16, 0, 0)

// ---------------- fp32 -> bf16 converts (merged launches) ----------------
__global__ __launch_bounds__(256) void k_cvt3(const float* __restrict__ a,
                                              const float* __restrict__ b,
                                              const float* __restrict__ c,
                                              u16* __restrict__ oa,
                                              u16* __restrict__ ob,
                                              u16* __restrict__ oc) {
  const float* s;
  u16* d;
  if (blockIdx.y == 0) { s = a; d = oa; }
  else if (blockIdx.y == 1) { s = b; d = ob; }
  else { s = c; d = oc; }
  int i = (blockIdx.x * 256 + threadIdx.x) * 4;
  float4 v = *(const float4*)(s + i);
  u64 p = (u64)f2bf(v.x) | ((u64)f2bf(v.y) << 16) | ((u64)f2bf(v.z) << 32) |
          ((u64)f2bf(v.w) << 48);
  *(u64*)(d + i) = p;
}

__global__ __launch_bounds__(256) void k_cvt4(const float* __restrict__ a,
                                              const float* __restrict__ b,
                                              const float* __restrict__ c,
                                              const float* __restrict__ e,
                                              u16* __restrict__ oa,
                                              u16* __restrict__ ob,
                                              u16* __restrict__ oc,
                                              u16* __restrict__ oe) {
  const float* s;
  u16* d;
  if (blockIdx.y == 0) { s = a; d = oa; }
  else if (blockIdx.y == 1) { s = b; d = ob; }
  else if (blockIdx.y == 2) { s = c; d = oc; }
  else { s = e; d = oe; }
  int i = (blockIdx.x * 256 + threadIdx.x) * 4;
  float4 v = *(const float4*)(s + i);
  u64 p = (u64)f2bf(v.x) | ((u64)f2bf(v.y) << 16) | ((u64)f2bf(v.z) << 32) |
          ((u64)f2bf(v.w) << 48);
  *(u64*)(d + i) = p;
}

// ---------------- mask -> 64-bit row bitmasks ----------------
__global__ __launch_bounds__(256) void k_bits(const float* __restrict__ mask,
                                              u64* __restrict__ bits) {
  int w = threadIdx.x >> 6, l = threadIdx.x & 63;
  int r = blockIdx.x * 4 + w;  // r in [0, 4096) = b*1024+s
  float v = mask[(size_t)r * 64 + l];
  u64 bl = __ballot(v != 0.0f);
  if (l == 0) bits[r] = bl;
}

// ---------------- mask bit-matrix: MB[qg][kt] bit j = row qg visible key kt*64+j
__global__ __launch_bounds__(256) void k_mm(const u64* __restrict__ bits,
                                            u64* __restrict__ MB) {
  int wv = threadIdx.x >> 6, l = threadIdx.x & 63;
  int qg = blockIdx.x * 4 + wv;  // 0..4095
  u64 bq = bits[qg];
  const u64* bb = bits + (qg & ~1023);
  u64* out = MB + (size_t)qg * 16;
  for (int kt = 0; kt < 16; kt++) {
    u64 bk = bb[kt * 64 + l];
    u64 m = __ballot((bq & bk) != 0ull);
    if (l == 0) out[kt] = m;
  }
}

// ------- shared GEMM core: C[128x128] = A[128xK] * B[128xK]^T --------------
static __device__ __forceinline__ void gemm_core(const u16* __restrict__ A,
                                                 const u16* __restrict__ Bw,
                                                 f32x4 (&acc)[4][4]) {
  __shared__ __attribute__((aligned(16))) u16 As[2][4096];
  __shared__ __attribute__((aligned(16))) u16 Bs[2][4096];
  const int t = threadIdx.x;
  const int l = t & 63, w = t >> 6, lr = l & 15, lk = l >> 4;
  const int amr = (w & 1) * 64, bnr = (w >> 1) * 64;
  const int c0 = t, c1 = t + 256;
  const int r0 = c0 >> 2, r1 = c1 >> 2;
  const int sw0 = ((c0 & 3) * 8) ^ ((r0 & 6) << 2);  // element offset in row
  const int sw1 = ((c1 & 3) * 8) ^ ((r1 & 6) << 2);
  const u16* Ag0 = A + (size_t)r0 * 1024 + sw0;
  const u16* Ag1 = A + (size_t)r1 * 1024 + sw1;
  const u16* Bg0 = Bw + (size_t)r0 * 1024 + sw0;
  const u16* Bg1 = Bw + (size_t)r1 * 1024 + sw1;
  const int aswz = (lk * 16) ^ ((lr & 6) << 3);  // byte offset in 64B row

  GLOAD_LDS16(Ag0, &As[0][c0 * 8]);
  GLOAD_LDS16(Ag1, &As[0][c1 * 8]);
  GLOAD_LDS16(Bg0, &Bs[0][c0 * 8]);
  GLOAD_LDS16(Bg1, &Bs[0][c1 * 8]);

  int cur = 0;
  for (int kt = 0; kt < 1024; kt += 32) {
    __syncthreads();  // drains cur loads + prev-iter LDS reads
    if (kt < 992) {
      const int nxt = cur ^ 1;
      GLOAD_LDS16(Ag0 + kt + 32, &As[nxt][c0 * 8]);
      GLOAD_LDS16(Ag1 + kt + 32, &As[nxt][c1 * 8]);
      GLOAD_LDS16(Bg0 + kt + 32, &Bs[nxt][c0 * 8]);
      GLOAD_LDS16(Bg1 + kt + 32, &Bs[nxt][c1 * 8]);
    }
    const char* Ac = (const char*)As[cur];
    const char* Bc = (const char*)Bs[cur];
    s16x8 af[4], bf[4];
#pragma unroll
    for (int i = 0; i < 4; i++)
      af[i] = *(const s16x8*)(Ac + (amr + i * 16 + lr) * 64 + aswz);
#pragma unroll
    for (int j = 0; j < 4; j++)
      bf[j] = *(const s16x8*)(Bc + (bnr + j * 16 + lr) * 64 + aswz);
    __builtin_amdgcn_s_setprio(1);
#pragma unroll
    for (int i = 0; i < 4; i++)
#pragma unroll
      for (int j = 0; j < 4; j++)
        acc[i][j] = mfma16x16(af[i], bf[j], acc[i][j]);
    __builtin_amdgcn_s_setprio(0);
    cur ^= 1;
  }
}

// ---------------- fused QKV projection ----------------
// Q/K: C^T orientation (rows=d, cols=s) -> packed b64 stores to [b,h][s][d].
// Q additionally scaled by QSC = log2(e)/8 (attn uses exp2 domain).
// V:   C orientation -> blocked V4[b,h][s>>3][d][s&7].
__global__ __launch_bounds__(256) void k_qkv(
    const u16* __restrict__ Xq, const u16* __restrict__ Xk,
    const u16* __restrict__ Xv, const u16* __restrict__ Wqb,
    const u16* __restrict__ Wkb, const u16* __restrict__ Wvb,
    const float* __restrict__ bq, const float* __restrict__ bk,
    const float* __restrict__ bv, u16* __restrict__ Qo, u16* __restrict__ Ko,
    u16* __restrict__ V4) {
  const int bid0 = blockIdx.x;
  const int bid = (bid0 & 7) * 96 + (bid0 >> 3);  // XCD swizzle (768%8==0)
  const int proj = bid >> 8;
  const int rem = bid & 255;
  const int st = rem >> 3, dt = rem & 7;
  const u16* Xp = proj == 0 ? Xq : (proj == 1 ? Xk : Xv);
  const u16* Wp = proj == 0 ? Wqb : (proj == 1 ? Wkb : Wvb);
  const float* bias = proj == 0 ? bq : (proj == 1 ? bk : bv);
  const int t = threadIdx.x;
  const int l = t & 63, w = t >> 6, lr = l & 15, lk = l >> 4;
  const int amr = (w & 1) * 64, bnr = (w >> 1) * 64;
  f32x4 acc[4][4] = {};
  if (proj < 2) {
    const float sc = proj == 0 ? QSC : 1.0f;
    gemm_core(Wp + (size_t)dt * 131072, Xp + (size_t)st * 131072, acc);
    u16* O = proj ? Ko : Qo;
#pragma unroll
    for (int i = 0; i < 4; i++) {
      const int d0 = dt * 128 + amr + i * 16 + lk * 4;
      const int h = d0 >> 6, dd0 = d0 & 63;
      const float4 b4 = *(const float4*)(bias + d0);
#pragma unroll
      for (int j = 0; j < 4; j++) {
        const int s = st * 128 + bnr + j * 16 + lr;
        const int b_ = s >> 10, si = s & 1023;
        u32 e0 = pkbf((acc[i][j][0] + b4.x) * sc, (acc[i][j][1] + b4.y) * sc);
        u32 e1 = pkbf((acc[i][j][2] + b4.z) * sc, (acc[i][j][3] + b4.w) * sc);
        *(u64*)(O + ((size_t)((b_ * 16 + h) * 1024 + si)) * 64 + dd0) =
            (u64)e0 | ((u64)e1 << 32);
      }
    }
  } else {
    gemm_core(Xp + (size_t)st * 131072, Wp + (size_t)dt * 131072, acc);
#pragma unroll
    for (int i = 0; i < 4; i++) {
      const int s0 = st * 128 + amr + i * 16 + lk * 4;
      const int b_ = s0 >> 10, si = s0 & 1023;
      const int sblk = si >> 3, soff = si & 7;
#pragma unroll
      for (int j = 0; j < 4; j++) {
        const int d = dt * 128 + bnr + j * 16 + lr;
        const int h = d >> 6, dd = d & 63;
        const float bb = bias[d];
        u32 e0 = pkbf(acc[i][j][0] + bb, acc[i][j][1] + bb);
        u32 e1 = pkbf(acc[i][j][2] + bb, acc[i][j][3] + bb);
        *(u64*)(V4 + (size_t)(b_ * 16 + h) * 65536 +
                (size_t)(sblk * 64 + dd) * 8 + soff) =
            (u64)e0 | ((u64)e1 << 32);
      }
    }
  }
}

// ---------------- output projection ----------------
__global__ __launch_bounds__(256) void k_oproj(const u16* __restrict__ Xb,
                                               const u16* __restrict__ Wob,
                                               float* __restrict__ Out) {
  const int bid0 = blockIdx.x;
  const int bid = (bid0 & 7) * 32 + (bid0 >> 3);  // XCD swizzle (256%8==0)
  const int mb = bid >> 3, nb = bid & 7;
  f32x4 acc[4][4] = {};
  gemm_core(Xb + (size_t)mb * 131072, Wob + (size_t)nb * 131072, acc);
  const int t = threadIdx.x;
  const int l = t & 63, w = t >> 6, lr = l & 15, lk = l >> 4;
  const int amr = (w & 1) * 64, bnr = (w >> 1) * 64;
#pragma unroll
  for (int i = 0; i < 4; i++)
#pragma unroll
    for (int j = 0; j < 4; j++)
#pragma unroll
      for (int r = 0; r < 4; r++) {
        const int m = mb * 128 + amr + i * 16 + lk * 4 + r;
        const int n = nb * 128 + bnr + j * 16 + lr;
        Out[(size_t)m * 1024 + n] = acc[i][j][r];
      }
}

// ---------------- flash attention: 32x32 MFMA, in-register P ---------------
// Wave owns 32 q (q = lane&31). QK^T: z = K*Q^T (rows=keys, cols=q).
// Softmax: EXACT online max (scl = 2^(m_old-m_new) rescale when tile max
// grows; tm shared across the (q,hi) lane pair via shfl_xor(32)).
// P redistribution lane<->lane+32 via v_permlane32_swap_b32 (no P LDS);
// semantics a.HI <-> b.LO, verified vs HK m214 recipe slot-by-slot.
// PV: out^T = V^T * P.
__global__ __launch_bounds__(256, 3) void k_attn(const u16* __restrict__ Qb,
                                                 const u16* __restrict__ Kb,
                                                 const u16* __restrict__ V4,
                                                 const u64* __restrict__ MB,
                                                 u16* __restrict__ xbuf) {
  __shared__ __attribute__((aligned(16))) u16 Ks[2][4096];
  __shared__ __attribute__((aligned(16))) u16 Vs[2][4096];
  const int t = threadIdx.x, l = t & 63, w = t >> 6;
  const int q5 = l & 31, hi = l >> 5;
  const int bid = (blockIdx.x & 7) * 64 + (blockIdx.x >> 3);  // XCD swizzle
  const int qt = bid & 7, hb = bid >> 3;
  const int h = hb >> 2, b = hb & 3;
  const int s0 = qt * 128;
  const u16* Qhb = Qb + (size_t)(b * 16 + h) * 65536;
  const u16* Khb = Kb + (size_t)(b * 16 + h) * 65536;
  const u16* Vhb = V4 + (size_t)(b * 16 + h) * 65536;
  const int q = s0 + w * 32 + q5;  // this lane's q (output column)
  const u64* MBq = MB + ((size_t)b * 1024 + q) * 16;

  // Q fragments (B-operand of 32x32x16): lane holds Q[q][ds*16 + hi*8 ..+7]
  s16x8 qf[4];
#pragma unroll
  for (int ds = 0; ds < 4; ds++)
    qf[ds] = *(const s16x8*)(Qhb + (size_t)q * 64 + ds * 16 + hi * 8);

  f32x16 xa0 = {}, xa1 = {};  // out^T rows d: xa0 d=0..31, xa1 d=32..63
  float ls = 0.f, m_ = -__builtin_inff();

  // staging geometry (pre-swizzled global source, linear LDS dest)
  const int ca = t, cb_ = t + 256;
  const int rA = ca >> 3, colA = (ca & 7) * 16;
  const int rB = cb_ >> 3, colB = (cb_ & 7) * 16;
  const int sA = colA ^ ((rA & 7) << 4);
  const int sB = colB ^ ((rB & 7) << 4);
  const u16* KgA = Khb + (size_t)rA * 64 + (sA >> 1);
  const u16* KgB = Khb + (size_t)rB * 64 + (sB >> 1);
  const u16* VgA = Vhb + (size_t)(sA >> 4) * 512 + rA * 8;
  const u16* VgB = Vhb + (size_t)(sB >> 4) * 512 + rB * 8;

  // per-lane read base: row q5 (keys for K / d for V), col hi*16, XOR-swizzled
  const int rbase = q5 * 128 + ((hi * 16) ^ ((q5 & 7) << 4));

  // prologue: stage tile 0; load tile-0 mask word
  GLOAD_LDS16(KgA, &Ks[0][ca * 8]);
  GLOAD_LDS16(KgB, &Ks[0][cb_ * 8]);
  GLOAD_LDS16(VgA, &Vs[0][ca * 8]);
  GLOAD_LDS16(VgB, &Vs[0][cb_ * 8]);
  u64 mw = MBq[0];

  int cur = 0;
  for (int kt = 0; kt < 16; kt++) {
    __syncthreads();  // drains cur-tile loads + prior compute
    if (kt < 15) {    // prefetch next tile into the other buffer
      const int nxt = cur ^ 1;
      GLOAD_LDS16(KgA + (kt + 1) * 4096, &Ks[nxt][ca * 8]);
      GLOAD_LDS16(KgB + (kt + 1) * 4096, &Ks[nxt][cb_ * 8]);
      GLOAD_LDS16(VgA + (kt + 1) * 4096, &Vs[nxt][ca * 8]);
      GLOAD_LDS16(VgB + (kt + 1) * 4096, &Vs[nxt][cb_ * 8]);
    }
    const u64 nw = MBq[(kt + 1) & 15];  // prefetch next mask word
    const char* Kc = (const char*)Ks[cur];
    const char* Vc = (const char*)Vs[cur];

    // QK^T: z0 = keys 0..31, z1 = keys 32..63 (rows), cols = q
    f32x16 z0 = {}, z1 = {};
#pragma unroll
    for (int ds = 0; ds < 4; ds++) {
      s16x8 k0 = *(const s16x8*)(Kc + (rbase ^ (ds * 32)));
      s16x8 k1 = *(const s16x8*)(Kc + 4096 + (rbase ^ (ds * 32)));
      __builtin_amdgcn_s_setprio(1);
      z0 = mfma32x32(k0, qf[ds], z0);
      z1 = mfma32x32(k1, qf[ds], z1);
      __builtin_amdgcn_s_setprio(0);
    }

    // exact online max over this tile's 64 keys for lane's q
    float tmx[16];
#pragma unroll
    for (int r = 0; r < 16; r++) tmx[r] = fmaxf(z0[r], z1[r]);
#pragma unroll
    for (int st_ = 8; st_ >= 1; st_ >>= 1)
#pragma unroll
      for (int r = 0; r < 8; r++)
        if (r < st_) tmx[r] = fmaxf(tmx[r], tmx[r + st_]);
    float tm = tmx[0];
    tm = fmaxf(tm, __shfl_xor(tm, 32));  // share across (q,hi) pair
    if (tm > m_) {
      const float scl = ex2(m_ - tm);  // ex2(-inf)=0 on first tile
      m_ = tm;
      ls *= scl;
      xa0 *= scl;
      xa1 *= scl;
    }

    // e = 2^(z - m), max-normalized (P in (0,1])
    float e0[16], e1[16];
#pragma unroll
    for (int r = 0; r < 16; r++) e0[r] = ex2(z0[r] - m_);
#pragma unroll
    for (int r = 0; r < 16; r++) e1[r] = ex2(z1[r] - m_);
    if (!__all(mw == ~0ull)) {  // mask is ~always all-pass; slow path exact
      const u32 mh0 = (u32)(mw >> (hi * 4));
      const u32 mh1 = (u32)(mw >> (hi * 4 + 32));
#pragma unroll
      for (int r = 0; r < 16; r++) {
        const int bp = 8 * (r >> 2) + (r & 3);
        e0[r] = ((mh0 >> bp) & 1u) ? e0[r] : 0.f;
        e1[r] = ((mh1 >> bp) & 1u) ? e1[r] : 0.f;
      }
    }
    float ts = 0.f;
#pragma unroll
    for (int r = 0; r < 16; r++) ts += e0[r] + e1[r];
    ls += ts;

    // pack quads to bf16 pairs:
    // P0[blk][qi] = keys(blk*32 + 8qi + 4hi + {0,1}), P1: {2,3}
    u32 P0[2][4], P1[2][4];
#pragma unroll
    for (int qi = 0; qi < 4; qi++) {
      P0[0][qi] = pkbf(e0[4 * qi], e0[4 * qi + 1]);
      P1[0][qi] = pkbf(e0[4 * qi + 2], e0[4 * qi + 3]);
      P0[1][qi] = pkbf(e1[4 * qi], e1[4 * qi + 1]);
      P1[1][qi] = pkbf(e1[4 * qi + 2], e1[4 * qi + 3]);
    }

    // PV over 4 key-slices; B-frag via permlane32_swap (a.HI <-> b.LO):
    // swap(P0[kb][qi0], P0[kb][qi1]) -> (word0, word2)
    // swap(P1[kb][qi0], P1[kb][qi1]) -> (word1, word3)
    // word j then holds keys ks*16 + hi*8 + {2j, 2j+1} for col q5.
#pragma unroll
    for (int ks = 0; ks < 4; ks++) {
      const int kb = ks >> 1, qi0 = (ks & 1) * 2, qi1 = qi0 + 1;
      u32 w0 = P0[kb][qi0], w2 = P0[kb][qi1];
      u32 w1 = P1[kb][qi0], w3 = P1[kb][qi1];
      asm("v_permlane32_swap_b32 %0, %1" : "+v"(w0), "+v"(w2));
      asm("v_permlane32_swap_b32 %0, %1" : "+v"(w1), "+v"(w3));
      u32x4 fv;
      fv[0] = w0; fv[1] = w1; fv[2] = w2; fv[3] = w3;
      const s16x8 pb = __builtin_bit_cast(s16x8, fv);
      s16x8 v0 = *(const s16x8*)(Vc + (rbase ^ (ks * 32)));
      s16x8 v1 = *(const s16x8*)(Vc + 4096 + (rbase ^ (ks * 32)));
      __builtin_amdgcn_s_setprio(1);
      xa0 = mfma32x32(v0, pb, xa0);
      xa1 = mfma32x32(v1, pb, xa1);
      __builtin_amdgcn_s_setprio(0);
    }
    mw = nw;
    cur ^= 1;
  }

  // epilogue: combine ls halves, normalize, write reference's mixed layout
  ls += __shfl_xor(ls, 32);
  const float inv = 1.0f / ls;
  const size_t rowb = (size_t)b * 1048576 + (size_t)(h * 64 + (q >> 4)) * 1024 +
                      (size_t)(q & 15) * 64;
#pragma unroll
  for (int qi = 0; qi < 4; qi++) {
    u32 a0 = pkbf(xa0[4 * qi] * inv, xa0[4 * qi + 1] * inv);
    u32 a1 = pkbf(xa0[4 * qi + 2] * inv, xa0[4 * qi + 3] * inv);
    *(u64*)(xbuf + rowb + 8 * qi + 4 * hi) = (u64)a0 | ((u64)a1 << 32);
    u32 b0 = pkbf(xa1[4 * qi] * inv, xa1[4 * qi + 1] * inv);
    u32 b1 = pkbf(xa1[4 * qi + 2] * inv, xa1[4 * qi + 3] * inv);
    *(u64*)(xbuf + rowb + 32 + 8 * qi + 4 * hi) = (u64)b0 | ((u64)b1 << 32);
  }
}

extern "C" void kernel_launch(void* const* d_in, const int* in_sizes, int n_in,
                              void* d_out, int out_size, void* d_ws,
                              size_t ws_size, hipStream_t stream) {
  const float* query = (const float*)d_in[0];
  const float* key_ = (const float*)d_in[1];
  const float* value = (const float*)d_in[2];
  const float* mask = (const float*)d_in[3];
  const float* bq = (const float*)d_in[5];
  const float* bk = (const float*)d_in[7];
  const float* bv = (const float*)d_in[9];
  const float* Wq = (const float*)d_in[4];
  const float* Wk = (const float*)d_in[6];
  const float* Wv = (const float*)d_in[8];
  const float* Wo = (const float*)d_in[10];

  char* ws = (char*)d_ws;
  u16* Xq = (u16*)(ws + 0 * WSMB);   // reused as xbuf after QKV GEMM
  u16* Xk = (u16*)(ws + 8 * WSMB);   // reused as MB after QKV GEMM
  u16* Xv = (u16*)(ws + 16 * WSMB);
  u16* Wqb = (u16*)(ws + 24 * WSMB);
  u16* Wkb = (u16*)(ws + 26 * WSMB);
  u16* Wvb = (u16*)(ws + 28 * WSMB);
  u16* Wob = (u16*)(ws + 30 * WSMB);
  u16* Qb = (u16*)(ws + 32 * WSMB);
  u16* Kb = (u16*)(ws + 40 * WSMB);
  u16* V4 = (u16*)(ws + 48 * WSMB);
  u64* bits = (u64*)(ws + 56 * WSMB);
  u64* MBm = (u64*)(ws + 8 * WSMB);  // 512 KB, overlaps dead Xk
  u16* xbuf = Xq;

  k_cvt3<<<dim3(4096, 3), 256, 0, stream>>>(query, key_, value, Xq, Xk, Xv);
  k_cvt4<<<dim3(1024, 4), 256, 0, stream>>>(Wq, Wk, Wv, Wo, Wqb, Wkb, Wvb, Wob);
  k_bits<<<1024, 256, 0, stream>>>(mask, bits);
  k_qkv<<<768, 256, 0, stream>>>(Xq, Xk, Xv, Wqb, Wkb, Wvb, bq, bk, bv, Qb, Kb,
                                 V4);
  k_mm<<<1024, 256, 0, stream>>>(bits, MBm);
  k_attn<<<512, 256, 0, stream>>>(Qb, Kb, V4, MBm, xbuf);
  k_oproj<<<256, 256, 0, stream>>>(xbuf, Wob, (float*)d_out);
}